// Round 1
// baseline (5966.240 us; speedup 1.0000x reference)
//
#include <hip/hip_runtime.h>
#include <math.h>

#define HW     17600   // 100*176 pixels
#define CD     256     // channels == D
#define LAG    5       // agents
#define NHEAD  8
#define DH     32
#define NT     3       // agent types

// ---------------------------------------------------------------------------
// Generic fp32 GEMM core: Y[64x64 tile] = A[Mx256] @ W[256x256] + bias[256]
// blockDim = 256, grid.x = M/64, grid.y = 256/64
// ---------------------------------------------------------------------------
__device__ __forceinline__ void gemm_core(
    const float* __restrict__ A, long lda,
    const float* __restrict__ W,        // [256][256] row-major (k, n)
    const float* __restrict__ bias,     // [256]
    float* __restrict__ Y, long ldy)
{
    __shared__ float As[16][64];   // As[k][m]
    __shared__ float Bs[16][64];   // Bs[k][n]

    const int t   = threadIdx.x;
    const int m0  = blockIdx.x * 64;
    const int n0  = blockIdx.y * 64;
    const int ty  = t >> 4;            // 0..15 (row group)
    const int tx  = t & 15;            // 0..15 (col group)
    const int arow = t >> 2;           // 0..63
    const int akc  = (t & 3) << 2;     // 0,4,8,12
    const int bkr  = t >> 4;           // 0..15
    const int bnc  = (t & 15) << 2;    // 0..60

    float acc[4][4] = {{0.f,0.f,0.f,0.f},{0.f,0.f,0.f,0.f},
                       {0.f,0.f,0.f,0.f},{0.f,0.f,0.f,0.f}};

    for (int k0 = 0; k0 < 256; k0 += 16) {
        float4 av = *(const float4*)(A + (long)(m0 + arow) * lda + (k0 + akc));
        float4 bv = *(const float4*)(W + (long)(k0 + bkr) * 256 + (n0 + bnc));
        __syncthreads();
        As[akc + 0][arow] = av.x;
        As[akc + 1][arow] = av.y;
        As[akc + 2][arow] = av.z;
        As[akc + 3][arow] = av.w;
        *(float4*)(&Bs[bkr][bnc]) = bv;
        __syncthreads();
#pragma unroll
        for (int kk = 0; kk < 16; ++kk) {
            float4 a4 = *(const float4*)(&As[kk][ty << 2]);
            float4 b4 = *(const float4*)(&Bs[kk][tx << 2]);
            float a[4] = {a4.x, a4.y, a4.z, a4.w};
            float b[4] = {b4.x, b4.y, b4.z, b4.w};
#pragma unroll
            for (int r = 0; r < 4; ++r)
#pragma unroll
                for (int c = 0; c < 4; ++c)
                    acc[r][c] = fmaf(a[r], b[c], acc[r][c]);
        }
    }

    const int nb = n0 + (tx << 2);
    float4 bz = *(const float4*)(bias + nb);
#pragma unroll
    for (int r = 0; r < 4; ++r) {
        int row = m0 + (ty << 2) + r;
        float4 o;
        o.x = acc[r][0] + bz.x;
        o.y = acc[r][1] + bz.y;
        o.z = acc[r][2] + bz.z;
        o.w = acc[r][3] + bz.w;
        *(float4*)(Y + (long)row * ldy + nb) = o;
    }
}

// ---------------------------------------------------------------------------
// Kernel 1: q/k/v projections. grid = (275, 4, 15): z = l*3 + proj
// ---------------------------------------------------------------------------
__global__ __launch_bounds__(256) void gemm_qkv_kernel(
    const float* __restrict__ x,    // [L][HW][C]
    const float* __restrict__ pe,   // [L][3]
    const float* __restrict__ Wq, const float* __restrict__ bq,
    const float* __restrict__ Wk, const float* __restrict__ bk,
    const float* __restrict__ Wv, const float* __restrict__ bv,
    float* __restrict__ qws, float* __restrict__ kws, float* __restrict__ vws)
{
    const int z = blockIdx.z;
    const int l = z / 3, proj = z % 3;
    const int tpe = (int)pe[l * 3 + 2];

    const float* A = x + (long)l * HW * CD;
    const float* W; const float* bias; float* Y;
    if      (proj == 0) { W = Wq; bias = bq; Y = qws; }
    else if (proj == 1) { W = Wk; bias = bk; Y = kws; }
    else                { W = Wv; bias = bv; Y = vws; }
    W    += (long)tpe * CD * CD;
    bias += tpe * CD;
    Y    += (long)l * HW * CD;

    gemm_core(A, CD, W, bias, Y, CD);
}

// ---------------------------------------------------------------------------
// Kernel 3: output projection. grid = (275, 4, 5): z = l
// A = attn ws, layout [pix][l][d] -> row stride 5*256 = 1280
// ---------------------------------------------------------------------------
__global__ __launch_bounds__(256) void gemm_out_kernel(
    const float* __restrict__ aws,  // [HW][L][256]
    const float* __restrict__ pe,
    const float* __restrict__ Wa, const float* __restrict__ ba,
    float* __restrict__ out)        // [L][HW][256]
{
    const int l = blockIdx.z;
    const int tpe = (int)pe[l * 3 + 2];

    const float* A = aws + (long)l * CD;          // row stride 1280
    const float* W = Wa + (long)tpe * CD * CD;
    const float* bias = ba + tpe * CD;
    float* Y = out + (long)l * HW * CD;

    gemm_core(A, (long)LAG * CD, W, bias, Y, CD);
}

// ---------------------------------------------------------------------------
// Kernel 2: per-pixel relational attention, one head per block.
// block = 512 threads = 16 pixel-slots x 32 lanes (lane = head dim p / c)
// grid = (275 pixel tiles of 64, 8 heads)
// ---------------------------------------------------------------------------
__global__ __launch_bounds__(512) void attn_kernel(
    const float* __restrict__ qws,   // [L][HW][256]
    const float* __restrict__ kws,
    const float* __restrict__ vws,
    const float* __restrict__ rel_att,  // [9][8][32][32]
    const float* __restrict__ rel_msg,  // [9][8][32][32]
    const int*   __restrict__ mask,     // [HW][L]
    const float* __restrict__ pe,       // [L][3]
    float* __restrict__ aws)            // [HW][L][256]
{
    const int m     = blockIdx.y;
    const int tile0 = blockIdx.x * 64;

    __shared__ float wattT[9][32][33];  // wattT[e][q][p] = rel_att[e][m][p][q] (padded)
    __shared__ float wmsg9[9][32][32];  // wmsg9[e][p][c] = rel_msg[e][m][p][c]
    __shared__ float ks[16][LAG][32];
    __shared__ float vs[16][LAG][32];

    const int t = threadIdx.x;
    // stage relation matrices for this head
    for (int idx = t; idx < 9 * 1024; idx += 512) {
        int e = idx >> 10, r = idx & 1023;
        int p = r >> 5, qq = r & 31;
        wattT[e][qq][p] = rel_att[((e * NHEAD + m) << 10) + r];
        wmsg9[e][p][qq] = rel_msg[((e * NHEAD + m) << 10) + r];
    }
    int ty[LAG];
#pragma unroll
    for (int l = 0; l < LAG; ++l) ty[l] = (int)pe[l * 3 + 2];
    __syncthreads();

    const int slot = t >> 5;
    const int lane = t & 31;
    const float scale = 0.17677669529663687f;  // 32^-0.5

    for (int it = 0; it < 4; ++it) {
        const int pix = tile0 + it * 16 + slot;

        float qr[LAG];
#pragma unroll
        for (int j = 0; j < LAG; ++j) {
            long off = ((long)j * HW + pix) * CD + m * DH + lane;
            qr[j] = qws[off];
            ks[slot][j][lane] = kws[off];
            vs[slot][j][lane] = vws[off];
        }
        int mk[LAG];
#pragma unroll
        for (int j = 0; j < LAG; ++j) mk[j] = mask[pix * LAG + j];
        __syncthreads();

        // ---- attention logits: att[i][j] = scale * sum_pq q[i,p] Watt[e][p][q] k[j,q]
        float att[LAG][LAG];
#pragma unroll
        for (int i = 0; i < LAG; ++i) {
#pragma unroll
            for (int j = 0; j < LAG; ++j) {
                const int e = ty[i] * NT + ty[j];
                const float* wp = &wattT[e][0][lane];   // stride 33 over q
                float kt = 0.f;
#pragma unroll
                for (int q4 = 0; q4 < 8; ++q4) {
                    float4 kb = *(const float4*)(&ks[slot][j][q4 << 2]);
                    kt = fmaf(wp[(q4 * 4 + 0) * 33], kb.x, kt);
                    kt = fmaf(wp[(q4 * 4 + 1) * 33], kb.y, kt);
                    kt = fmaf(wp[(q4 * 4 + 2) * 33], kb.z, kt);
                    kt = fmaf(wp[(q4 * 4 + 3) * 33], kb.w, kt);
                }
                float part = qr[i] * kt;
#pragma unroll
                for (int o = 16; o > 0; o >>= 1) part += __shfl_xor(part, o, 32);
                att[i][j] = part * scale;
            }
        }

        // ---- masked softmax over j
#pragma unroll
        for (int i = 0; i < LAG; ++i) {
            float mx = -INFINITY;
#pragma unroll
            for (int j = 0; j < LAG; ++j) {
                att[i][j] = mk[j] ? att[i][j] : -INFINITY;
                mx = fmaxf(mx, att[i][j]);
            }
            float s = 0.f;
#pragma unroll
            for (int j = 0; j < LAG; ++j) {
                att[i][j] = __expf(att[i][j] - mx);
                s += att[i][j];
            }
            float inv = 1.f / s;
#pragma unroll
            for (int j = 0; j < LAG; ++j) att[i][j] *= inv;
        }

        // ---- out[i][c] = sum_j att[i][j] * sum_p Wmsg[e][p][c] v[j][p]
#pragma unroll
        for (int i = 0; i < LAG; ++i) {
            float acc = 0.f;
#pragma unroll
            for (int j = 0; j < LAG; ++j) {
                const int e = ty[i] * NT + ty[j];
                const float* wp = &wmsg9[e][0][lane];   // stride 32 over p
                float mv = 0.f;
#pragma unroll
                for (int p4 = 0; p4 < 8; ++p4) {
                    float4 vb = *(const float4*)(&vs[slot][j][p4 << 2]);
                    mv = fmaf(wp[(p4 * 4 + 0) * 32], vb.x, mv);
                    mv = fmaf(wp[(p4 * 4 + 1) * 32], vb.y, mv);
                    mv = fmaf(wp[(p4 * 4 + 2) * 32], vb.z, mv);
                    mv = fmaf(wp[(p4 * 4 + 3) * 32], vb.w, mv);
                }
                acc = fmaf(att[i][j], mv, acc);
            }
            aws[((long)pix * LAG + i) * CD + m * DH + lane] = acc;
        }
        __syncthreads();
    }
}

// ---------------------------------------------------------------------------
extern "C" void kernel_launch(void* const* d_in, const int* in_sizes, int n_in,
                              void* d_out, int out_size, void* d_ws, size_t ws_size,
                              hipStream_t stream) {
    const float* x    = (const float*)d_in[0];
    const int*   mask = (const int*)  d_in[1];
    const float* pe   = (const float*)d_in[2];
    const float* Wq   = (const float*)d_in[3];
    const float* bq   = (const float*)d_in[4];
    const float* Wk   = (const float*)d_in[5];
    const float* bk   = (const float*)d_in[6];
    const float* Wv   = (const float*)d_in[7];
    const float* bv   = (const float*)d_in[8];
    const float* Wa   = (const float*)d_in[9];
    const float* ba   = (const float*)d_in[10];
    const float* ratt = (const float*)d_in[11];
    const float* rmsg = (const float*)d_in[12];
    float* out = (float*)d_out;

    const size_t PLANE = (size_t)LAG * HW * CD;   // 22,528,000 floats
    float* qws = (float*)d_ws;
    float* kws = qws + PLANE;
    float* vws = kws + PLANE;
    float* aws = vws + PLANE;   // [HW][L][256]

    dim3 g1(HW / 64, 4, LAG * 3);
    gemm_qkv_kernel<<<g1, 256, 0, stream>>>(x, pe, Wq, bq, Wk, bk, Wv, bv,
                                            qws, kws, vws);

    dim3 g2(HW / 64, NHEAD);
    attn_kernel<<<g2, 512, 0, stream>>>(qws, kws, vws, ratt, rmsg, mask, pe, aws);

    dim3 g3(HW / 64, 4, LAG);
    gemm_out_kernel<<<g3, 256, 0, stream>>>(aws, pe, Wa, ba, out);
}

// Round 2
// 5847.289 us; speedup vs baseline: 1.0203x; 1.0203x over previous
//
#include <hip/hip_runtime.h>
#include <math.h>

#define HW     17600   // 100*176 pixels
#define CD     256     // channels == D
#define LAG    5       // agents
#define NHEAD  8
#define DH     32
#define NT     3       // agent types

// ---------------------------------------------------------------------------
// Generic fp32 GEMM core: Y[64x64 tile] = A[Mx256] @ W[256x256] + bias[256]
// blockDim = 256, grid.x = M/64, grid.y = 256/64
// ---------------------------------------------------------------------------
__device__ __forceinline__ void gemm_core(
    const float* __restrict__ A, long lda,
    const float* __restrict__ W,        // [256][256] row-major (k, n)
    const float* __restrict__ bias,     // [256]
    float* __restrict__ Y, long ldy)
{
    __shared__ float As[16][64];   // As[k][m]
    __shared__ float Bs[16][64];   // Bs[k][n]

    const int t   = threadIdx.x;
    const int m0  = blockIdx.x * 64;
    const int n0  = blockIdx.y * 64;
    const int ty  = t >> 4;            // 0..15 (row group)
    const int tx  = t & 15;            // 0..15 (col group)
    const int arow = t >> 2;           // 0..63
    const int akc  = (t & 3) << 2;     // 0,4,8,12
    const int bkr  = t >> 4;           // 0..15
    const int bnc  = (t & 15) << 2;    // 0..60

    float acc[4][4] = {{0.f,0.f,0.f,0.f},{0.f,0.f,0.f,0.f},
                       {0.f,0.f,0.f,0.f},{0.f,0.f,0.f,0.f}};

    for (int k0 = 0; k0 < 256; k0 += 16) {
        float4 av = *(const float4*)(A + (long)(m0 + arow) * lda + (k0 + akc));
        float4 bv = *(const float4*)(W + (long)(k0 + bkr) * 256 + (n0 + bnc));
        __syncthreads();
        As[akc + 0][arow] = av.x;
        As[akc + 1][arow] = av.y;
        As[akc + 2][arow] = av.z;
        As[akc + 3][arow] = av.w;
        *(float4*)(&Bs[bkr][bnc]) = bv;
        __syncthreads();
#pragma unroll
        for (int kk = 0; kk < 16; ++kk) {
            float4 a4 = *(const float4*)(&As[kk][ty << 2]);
            float4 b4 = *(const float4*)(&Bs[kk][tx << 2]);
            float a[4] = {a4.x, a4.y, a4.z, a4.w};
            float b[4] = {b4.x, b4.y, b4.z, b4.w};
#pragma unroll
            for (int r = 0; r < 4; ++r)
#pragma unroll
                for (int c = 0; c < 4; ++c)
                    acc[r][c] = fmaf(a[r], b[c], acc[r][c]);
        }
    }

    const int nb = n0 + (tx << 2);
    float4 bz = *(const float4*)(bias + nb);
#pragma unroll
    for (int r = 0; r < 4; ++r) {
        int row = m0 + (ty << 2) + r;
        float4 o;
        o.x = acc[r][0] + bz.x;
        o.y = acc[r][1] + bz.y;
        o.z = acc[r][2] + bz.z;
        o.w = acc[r][3] + bz.w;
        *(float4*)(Y + (long)row * ldy + nb) = o;
    }
}

// ---------------------------------------------------------------------------
// Kernel 1: q/k/v projections. grid = (275, 4, 15): z = l*3 + proj
// ---------------------------------------------------------------------------
__global__ __launch_bounds__(256) void gemm_qkv_kernel(
    const float* __restrict__ x,    // [L][HW][C]
    const float* __restrict__ pe,   // [L][3]
    const float* __restrict__ Wq, const float* __restrict__ bq,
    const float* __restrict__ Wk, const float* __restrict__ bk,
    const float* __restrict__ Wv, const float* __restrict__ bv,
    float* __restrict__ qws, float* __restrict__ kws, float* __restrict__ vws)
{
    const int z = blockIdx.z;
    const int l = z / 3, proj = z % 3;
    const int tpe = (int)pe[l * 3 + 2];

    const float* A = x + (long)l * HW * CD;
    const float* W; const float* bias; float* Y;
    if      (proj == 0) { W = Wq; bias = bq; Y = qws; }
    else if (proj == 1) { W = Wk; bias = bk; Y = kws; }
    else                { W = Wv; bias = bv; Y = vws; }
    W    += (long)tpe * CD * CD;
    bias += tpe * CD;
    Y    += (long)l * HW * CD;

    gemm_core(A, CD, W, bias, Y, CD);
}

// ---------------------------------------------------------------------------
// Kernel 3: output projection. grid = (275, 4, 5): z = l
// ---------------------------------------------------------------------------
__global__ __launch_bounds__(256) void gemm_out_kernel(
    const float* __restrict__ aws,  // [HW][L][256]
    const float* __restrict__ pe,
    const float* __restrict__ Wa, const float* __restrict__ ba,
    float* __restrict__ out)        // [L][HW][256]
{
    const int l = blockIdx.z;
    const int tpe = (int)pe[l * 3 + 2];

    const float* A = aws + (long)l * CD;          // row stride 1280
    const float* W = Wa + (long)tpe * CD * CD;
    const float* bias = ba + tpe * CD;
    float* Y = out + (long)l * HW * CD;

    gemm_core(A, (long)LAG * CD, W, bias, Y, CD);
}

// ---------------------------------------------------------------------------
// Kernel P: relational precompute.
//   ktil[tau*5+j][pix][m*32+p] = sum_q Watt[tau*3+ty_j][m][p][q] * k[j][pix][m*32+q]
//   vtil[tau*5+j][pix][m*32+c] = sum_p Wmsg[tau*3+ty_j][m][p][c] * v[j][pix][m*32+p]
// grid = (ceil(HW/128), 8 heads, 15 tau*5+j), block = 256.
// Threads 0..127 (waves 0,1) do ktil, 128..255 (waves 2,3) do vtil.
// W address is block-uniform -> s_load + SGPR-operand FMAs.
// ---------------------------------------------------------------------------
__global__ __launch_bounds__(256) void rel_precompute_kernel(
    const float* __restrict__ kws, const float* __restrict__ vws,
    const float* __restrict__ rel_att, const float* __restrict__ rel_msg,
    const float* __restrict__ pe,
    float* __restrict__ ktil, float* __restrict__ vtil)
{
    const int z   = blockIdx.z;         // tau*5 + j
    const int tau = z / 5, j = z % 5;
    const int m   = blockIdx.y;
    const int t   = threadIdx.x;
    const int half = t >> 7;            // wave-uniform
    const int pix  = blockIdx.x * 128 + (t & 127);

    // skip tau values not present among agent types
    bool present = false;
#pragma unroll
    for (int l = 0; l < LAG; ++l) present = present || ((int)pe[l * 3 + 2] == tau);
    if (!present) return;
    if (pix >= HW) return;

    const int tyj = (int)pe[j * 3 + 2];
    const int e   = tau * NT + tyj;

    const float* __restrict__ W   = (half ? rel_msg : rel_att) + ((long)(e * NHEAD + m) << 10);
    const float* __restrict__ src = (half ? vws : kws) + ((long)j * HW + pix) * CD + m * DH;
    float*       __restrict__ dst = (half ? vtil : ktil) + ((long)z * HW + pix) * CD + m * DH;

    float in[32];
#pragma unroll
    for (int c4 = 0; c4 < 8; ++c4) {
        float4 v = *(const float4*)(src + (c4 << 2));
        in[c4 * 4 + 0] = v.x; in[c4 * 4 + 1] = v.y;
        in[c4 * 4 + 2] = v.z; in[c4 * 4 + 3] = v.w;
    }

    float acc[32];
#pragma unroll
    for (int p = 0; p < 32; ++p) acc[p] = 0.f;

    if (half == 0) {
        // acc[p] = sum_q W[p][q] * in[q]
#pragma unroll
        for (int p = 0; p < 32; ++p) {
            float s = 0.f;
#pragma unroll
            for (int q = 0; q < 32; ++q) s = fmaf(W[p * 32 + q], in[q], s);
            acc[p] = s;
        }
    } else {
        // acc[c] = sum_p W[p][c] * in[p]
#pragma unroll
        for (int p = 0; p < 32; ++p) {
            const float ip = in[p];
#pragma unroll
            for (int c = 0; c < 32; ++c) acc[c] = fmaf(W[p * 32 + c], ip, acc[c]);
        }
    }

#pragma unroll
    for (int c4 = 0; c4 < 8; ++c4) {
        float4 v;
        v.x = acc[c4 * 4 + 0]; v.y = acc[c4 * 4 + 1];
        v.z = acc[c4 * 4 + 2]; v.w = acc[c4 * 4 + 3];
        *(float4*)(dst + (c4 << 2)) = v;
    }
}

// ---------------------------------------------------------------------------
// Kernel 2 (light): per (pixel, head) attention from precomputed ktil/vtil.
// 256 threads/block; each 32-lane group owns one (pixel, head); lane = p/c.
// grid.x = HW*NHEAD*32/256 = 17600. No LDS, ~80 VGPRs, fully static indexing.
// ---------------------------------------------------------------------------
__global__ __launch_bounds__(256) void attn_light_kernel(
    const float* __restrict__ qws,   // [L][HW][256]
    const float* __restrict__ ktil,  // [15][HW][256]
    const float* __restrict__ vtil,  // [15][HW][256]
    const int*   __restrict__ mask,  // [HW][L]
    const float* __restrict__ pe,
    float* __restrict__ aws)         // [HW][L][256]
{
    const int gid  = blockIdx.x * 256 + threadIdx.x;
    const int lane = threadIdx.x & 31;
    const int grp  = gid >> 5;       // pix*8 + m
    const int m    = grp & 7;
    const int pix  = grp >> 3;

    int ty[LAG];
#pragma unroll
    for (int l = 0; l < LAG; ++l) ty[l] = (int)pe[l * 3 + 2];
    bool p0 = false, p1 = false, p2 = false;
#pragma unroll
    for (int l = 0; l < LAG; ++l) {
        p0 = p0 || (ty[l] == 0); p1 = p1 || (ty[l] == 1); p2 = p2 || (ty[l] == 2);
    }

    const long base  = (long)pix * CD + m * DH + lane;  // offset within one plane
    const long PL    = (long)HW * CD;

    float qv[LAG];
#pragma unroll
    for (int i = 0; i < LAG; ++i) qv[i] = qws[(long)i * PL + base];

    float kt0[LAG], kt1[LAG], kt2[LAG];
#pragma unroll
    for (int j = 0; j < LAG; ++j) {
        kt0[j] = p0 ? ktil[(long)(0 * LAG + j) * PL + base] : 0.f;
        kt1[j] = p1 ? ktil[(long)(1 * LAG + j) * PL + base] : 0.f;
        kt2[j] = p2 ? ktil[(long)(2 * LAG + j) * PL + base] : 0.f;
    }

    int mk[LAG];
#pragma unroll
    for (int j = 0; j < LAG; ++j) mk[j] = mask[pix * LAG + j];

    const float scale = 0.17677669529663687f;  // 32^-0.5
    float att[LAG][LAG];
#pragma unroll
    for (int i = 0; i < LAG; ++i) {
        const int tyi = ty[i];
#pragma unroll
        for (int j = 0; j < LAG; ++j) {
            float kt = (tyi == 0) ? kt0[j] : ((tyi == 1) ? kt1[j] : kt2[j]);
            float part = qv[i] * kt;
#pragma unroll
            for (int o = 16; o > 0; o >>= 1) part += __shfl_xor(part, o, 32);
            att[i][j] = part * scale;
        }
    }

    // masked softmax over j
#pragma unroll
    for (int i = 0; i < LAG; ++i) {
        float mx = -INFINITY;
#pragma unroll
        for (int j = 0; j < LAG; ++j) {
            att[i][j] = mk[j] ? att[i][j] : -INFINITY;
            mx = fmaxf(mx, att[i][j]);
        }
        float s = 0.f;
#pragma unroll
        for (int j = 0; j < LAG; ++j) {
            att[i][j] = __expf(att[i][j] - mx);
            s += att[i][j];
        }
        float inv = 1.f / s;
#pragma unroll
        for (int j = 0; j < LAG; ++j) att[i][j] *= inv;
    }

    float vt0[LAG], vt1[LAG], vt2[LAG];
#pragma unroll
    for (int j = 0; j < LAG; ++j) {
        vt0[j] = p0 ? vtil[(long)(0 * LAG + j) * PL + base] : 0.f;
        vt1[j] = p1 ? vtil[(long)(1 * LAG + j) * PL + base] : 0.f;
        vt2[j] = p2 ? vtil[(long)(2 * LAG + j) * PL + base] : 0.f;
    }

#pragma unroll
    for (int i = 0; i < LAG; ++i) {
        const int tyi = ty[i];
        float acc = 0.f;
#pragma unroll
        for (int j = 0; j < LAG; ++j) {
            float mv = (tyi == 0) ? vt0[j] : ((tyi == 1) ? vt1[j] : vt2[j]);
            acc = fmaf(att[i][j], mv, acc);
        }
        aws[((long)pix * LAG + i) * CD + m * DH + lane] = acc;
    }
}

// ---------------------------------------------------------------------------
// Fallback fused attention (round-1 kernel) for small workspaces.
// ---------------------------------------------------------------------------
__global__ __launch_bounds__(512) void attn_kernel(
    const float* __restrict__ qws, const float* __restrict__ kws,
    const float* __restrict__ vws,
    const float* __restrict__ rel_att, const float* __restrict__ rel_msg,
    const int*   __restrict__ mask, const float* __restrict__ pe,
    float* __restrict__ aws)
{
    const int m     = blockIdx.y;
    const int tile0 = blockIdx.x * 64;

    __shared__ float wattT[9][32][33];
    __shared__ float wmsg9[9][32][32];
    __shared__ float ks[16][LAG][32];
    __shared__ float vs[16][LAG][32];

    const int t = threadIdx.x;
    for (int idx = t; idx < 9 * 1024; idx += 512) {
        int e = idx >> 10, r = idx & 1023;
        int p = r >> 5, qq = r & 31;
        wattT[e][qq][p] = rel_att[((e * NHEAD + m) << 10) + r];
        wmsg9[e][p][qq] = rel_msg[((e * NHEAD + m) << 10) + r];
    }
    int ty[LAG];
#pragma unroll
    for (int l = 0; l < LAG; ++l) ty[l] = (int)pe[l * 3 + 2];
    __syncthreads();

    const int slot = t >> 5;
    const int lane = t & 31;
    const float scale = 0.17677669529663687f;

    for (int it = 0; it < 4; ++it) {
        const int pix = tile0 + it * 16 + slot;
        float qr[LAG];
#pragma unroll
        for (int j = 0; j < LAG; ++j) {
            long off = ((long)j * HW + pix) * CD + m * DH + lane;
            qr[j] = qws[off];
            ks[slot][j][lane] = kws[off];
            vs[slot][j][lane] = vws[off];
        }
        int mk[LAG];
#pragma unroll
        for (int j = 0; j < LAG; ++j) mk[j] = mask[pix * LAG + j];
        __syncthreads();

        float att[LAG][LAG];
#pragma unroll
        for (int i = 0; i < LAG; ++i) {
#pragma unroll
            for (int j = 0; j < LAG; ++j) {
                const int e = ty[i] * NT + ty[j];
                const float* wp = &wattT[e][0][lane];
                float kt = 0.f;
#pragma unroll
                for (int q4 = 0; q4 < 8; ++q4) {
                    float4 kb = *(const float4*)(&ks[slot][j][q4 << 2]);
                    kt = fmaf(wp[(q4 * 4 + 0) * 33], kb.x, kt);
                    kt = fmaf(wp[(q4 * 4 + 1) * 33], kb.y, kt);
                    kt = fmaf(wp[(q4 * 4 + 2) * 33], kb.z, kt);
                    kt = fmaf(wp[(q4 * 4 + 3) * 33], kb.w, kt);
                }
                float part = qr[i] * kt;
#pragma unroll
                for (int o = 16; o > 0; o >>= 1) part += __shfl_xor(part, o, 32);
                att[i][j] = part * scale;
            }
        }
#pragma unroll
        for (int i = 0; i < LAG; ++i) {
            float mx = -INFINITY;
#pragma unroll
            for (int j = 0; j < LAG; ++j) {
                att[i][j] = mk[j] ? att[i][j] : -INFINITY;
                mx = fmaxf(mx, att[i][j]);
            }
            float s = 0.f;
#pragma unroll
            for (int j = 0; j < LAG; ++j) { att[i][j] = __expf(att[i][j] - mx); s += att[i][j]; }
            float inv = 1.f / s;
#pragma unroll
            for (int j = 0; j < LAG; ++j) att[i][j] *= inv;
        }
#pragma unroll
        for (int i = 0; i < LAG; ++i) {
            float acc = 0.f;
#pragma unroll
            for (int j = 0; j < LAG; ++j) {
                const int e = ty[i] * NT + ty[j];
                const float* wp = &wmsg9[e][0][lane];
                float mv = 0.f;
#pragma unroll
                for (int p4 = 0; p4 < 8; ++p4) {
                    float4 vb = *(const float4*)(&vs[slot][j][p4 << 2]);
                    mv = fmaf(wp[(p4 * 4 + 0) * 32], vb.x, mv);
                    mv = fmaf(wp[(p4 * 4 + 1) * 32], vb.y, mv);
                    mv = fmaf(wp[(p4 * 4 + 2) * 32], vb.z, mv);
                    mv = fmaf(wp[(p4 * 4 + 3) * 32], vb.w, mv);
                }
                acc = fmaf(att[i][j], mv, acc);
            }
            aws[((long)pix * LAG + i) * CD + m * DH + lane] = acc;
        }
        __syncthreads();
    }
}

// ---------------------------------------------------------------------------
extern "C" void kernel_launch(void* const* d_in, const int* in_sizes, int n_in,
                              void* d_out, int out_size, void* d_ws, size_t ws_size,
                              hipStream_t stream) {
    const float* x    = (const float*)d_in[0];
    const int*   mask = (const int*)  d_in[1];
    const float* pe   = (const float*)d_in[2];
    const float* Wq   = (const float*)d_in[3];
    const float* bq   = (const float*)d_in[4];
    const float* Wk   = (const float*)d_in[5];
    const float* bk   = (const float*)d_in[6];
    const float* Wv   = (const float*)d_in[7];
    const float* bv   = (const float*)d_in[8];
    const float* Wa   = (const float*)d_in[9];
    const float* ba   = (const float*)d_in[10];
    const float* ratt = (const float*)d_in[11];
    const float* rmsg = (const float*)d_in[12];
    float* out = (float*)d_out;

    const size_t PLANE  = (size_t)LAG * HW * CD;          // 22,528,000 floats
    const size_t TPLANE = (size_t)NT * LAG * HW * CD;     // 67,584,000 floats
    const size_t need_fast = (3 * PLANE + 2 * TPLANE) * sizeof(float);  // ~811 MB

    float* qws = (float*)d_ws;
    float* kws = qws + PLANE;
    float* vws = kws + PLANE;

    dim3 g1(HW / 64, 4, LAG * 3);
    gemm_qkv_kernel<<<g1, 256, 0, stream>>>(x, pe, Wq, bq, Wk, bk, Wv, bv,
                                            qws, kws, vws);

    float* aws;
    if (ws_size >= need_fast) {
        float* ktil = vws + PLANE;
        float* vtil = ktil + TPLANE;
        aws = kws;   // kws is dead after precompute; reuse as attention output

        dim3 gp((HW + 127) / 128, NHEAD, NT * LAG);
        rel_precompute_kernel<<<gp, 256, 0, stream>>>(kws, vws, ratt, rmsg, pe,
                                                      ktil, vtil);

        dim3 ga(HW);  // HW*NHEAD*32 / 256
        attn_light_kernel<<<ga, 256, 0, stream>>>(qws, ktil, vtil, mask, pe, aws);
    } else {
        aws = vws + PLANE;
        dim3 g2(HW / 64, NHEAD);
        attn_kernel<<<g2, 512, 0, stream>>>(qws, kws, vws, ratt, rmsg, mask, pe, aws);
    }

    dim3 g3(HW / 64, 4, LAG);
    gemm_out_kernel<<<g3, 256, 0, stream>>>(aws, pe, Wa, ba, out);
}

// Round 3
// 1423.971 us; speedup vs baseline: 4.1899x; 4.1063x over previous
//
#include <hip/hip_runtime.h>
#include <math.h>

#define HW     17600   // 100*176 pixels
#define CD     256     // channels == D
#define LAG    5       // agents
#define NHEAD  8
#define DH     32
#define NT     3       // agent types
#define CHUNK  4400    // HW/4 pixel chunk for ktil/vtil staging
#define NCHUNK 4

// ---- bf16 helpers (OCP bf16 as raw ushort) --------------------------------
__device__ __forceinline__ float bfu(unsigned short v) {
    return __uint_as_float(((unsigned)v) << 16);
}
__device__ __forceinline__ unsigned f2bf(float f) {
    unsigned u = __float_as_uint(f);
    return (u + 0x7fffu + ((u >> 16) & 1u)) >> 16;   // RNE
}
__device__ __forceinline__ unsigned pack2(float a, float b) {
    return f2bf(a) | (f2bf(b) << 16);
}

// ---------------------------------------------------------------------------
// GEMM core: Y[64x64 tile] = A[Mx256] @ W[256x256] + bias[256]
// A may be bf16 (ABF) and Y may be bf16 (YBF). blockDim=256.
// ---------------------------------------------------------------------------
template<bool ABF, bool YBF>
__device__ __forceinline__ void gemm_core_t(
    const void* __restrict__ Av, long lda,
    const float* __restrict__ W,        // [256][256] row-major (k, n), fp32
    const float* __restrict__ bias,     // [256] fp32
    void* __restrict__ Yv, long ldy)
{
    __shared__ float As[16][64];   // As[k][m]
    __shared__ float Bs[16][64];   // Bs[k][n]

    const int t   = threadIdx.x;
    const int m0  = blockIdx.x * 64;
    const int n0  = blockIdx.y * 64;
    const int ty  = t >> 4;
    const int tx  = t & 15;
    const int arow = t >> 2;
    const int akc  = (t & 3) << 2;
    const int bkr  = t >> 4;
    const int bnc  = (t & 15) << 2;

    float acc[4][4] = {{0.f,0.f,0.f,0.f},{0.f,0.f,0.f,0.f},
                       {0.f,0.f,0.f,0.f},{0.f,0.f,0.f,0.f}};

    for (int k0 = 0; k0 < 256; k0 += 16) {
        float4 av;
        if (ABF) {
            uint2 u = *(const uint2*)((const unsigned short*)Av +
                                      (long)(m0 + arow) * lda + (k0 + akc));
            av.x = __uint_as_float(u.x << 16);
            av.y = __uint_as_float(u.x & 0xffff0000u);
            av.z = __uint_as_float(u.y << 16);
            av.w = __uint_as_float(u.y & 0xffff0000u);
        } else {
            av = *(const float4*)((const float*)Av +
                                  (long)(m0 + arow) * lda + (k0 + akc));
        }
        float4 bv = *(const float4*)(W + (long)(k0 + bkr) * 256 + (n0 + bnc));
        __syncthreads();
        As[akc + 0][arow] = av.x;
        As[akc + 1][arow] = av.y;
        As[akc + 2][arow] = av.z;
        As[akc + 3][arow] = av.w;
        *(float4*)(&Bs[bkr][bnc]) = bv;
        __syncthreads();
#pragma unroll
        for (int kk = 0; kk < 16; ++kk) {
            float4 a4 = *(const float4*)(&As[kk][ty << 2]);
            float4 b4 = *(const float4*)(&Bs[kk][tx << 2]);
            float a[4] = {a4.x, a4.y, a4.z, a4.w};
            float b[4] = {b4.x, b4.y, b4.z, b4.w};
#pragma unroll
            for (int r = 0; r < 4; ++r)
#pragma unroll
                for (int c = 0; c < 4; ++c)
                    acc[r][c] = fmaf(a[r], b[c], acc[r][c]);
        }
    }

    const int nb = n0 + (tx << 2);
    float4 bz = *(const float4*)(bias + nb);
#pragma unroll
    for (int r = 0; r < 4; ++r) {
        int row = m0 + (ty << 2) + r;
        float o0 = acc[r][0] + bz.x;
        float o1 = acc[r][1] + bz.y;
        float o2 = acc[r][2] + bz.z;
        float o3 = acc[r][3] + bz.w;
        if (YBF) {
            uint2 o;
            o.x = pack2(o0, o1);
            o.y = pack2(o2, o3);
            *(uint2*)((unsigned short*)Yv + (long)row * ldy + nb) = o;
        } else {
            float4 o; o.x = o0; o.y = o1; o.z = o2; o.w = o3;
            *(float4*)((float*)Yv + (long)row * ldy + nb) = o;
        }
    }
}

// ---------------------------------------------------------------------------
// Kernel 1: q/k/v projections -> bf16 planes. grid = (275, 4, 15)
// ---------------------------------------------------------------------------
__global__ __launch_bounds__(256) void gemm_qkv_kernel(
    const float* __restrict__ x,    // [L][HW][C] fp32
    const float* __restrict__ pe,
    const float* __restrict__ Wq, const float* __restrict__ bq,
    const float* __restrict__ Wk, const float* __restrict__ bk,
    const float* __restrict__ Wv, const float* __restrict__ bv,
    unsigned short* __restrict__ qws,
    unsigned short* __restrict__ kws,
    unsigned short* __restrict__ vws)
{
    const int z = blockIdx.z;
    const int l = z / 3, proj = z % 3;
    const int tpe = (int)pe[l * 3 + 2];

    const float* A = x + (long)l * HW * CD;
    const float* W; const float* bias; unsigned short* Y;
    if      (proj == 0) { W = Wq; bias = bq; Y = qws; }
    else if (proj == 1) { W = Wk; bias = bk; Y = kws; }
    else                { W = Wv; bias = bv; Y = vws; }
    W    += (long)tpe * CD * CD;
    bias += tpe * CD;
    Y    += (long)l * HW * CD;

    gemm_core_t<false, true>(A, CD, W, bias, Y, CD);
}

// ---------------------------------------------------------------------------
// Kernel 3: output projection. A = aws bf16 [HW][L][256], out fp32 [L][HW][256]
// ---------------------------------------------------------------------------
__global__ __launch_bounds__(256) void gemm_out_kernel(
    const unsigned short* __restrict__ aws,
    const float* __restrict__ pe,
    const float* __restrict__ Wa, const float* __restrict__ ba,
    float* __restrict__ out)
{
    const int l = blockIdx.z;
    const int tpe = (int)pe[l * 3 + 2];

    const unsigned short* A = aws + (long)l * CD;   // row stride 1280 elems
    const float* W = Wa + (long)tpe * CD * CD;
    const float* bias = ba + tpe * CD;
    float* Y = out + (long)l * HW * CD;

    gemm_core_t<true, false>(A, (long)LAG * CD, W, bias, Y, CD);
}

// ---------------------------------------------------------------------------
// Kernel P: relational precompute into chunk-local bf16 buffers.
//   ktil[tau*5+j][pl][m*32+p] = sum_q Watt[tau*3+ty_j][m][p][q] * k[j][pix][m*32+q]
//   vtil[tau*5+j][pl][m*32+c] = sum_p Wmsg[tau*3+ty_j][m][p][c] * v[j][pix][m*32+p]
// grid = (ceil(CHUNK/128), 8, 15), block = 256 (lower half ktil, upper vtil).
// W address is uniform -> s_load + SGPR-operand FMAs, no LDS.
// ---------------------------------------------------------------------------
__global__ __launch_bounds__(256) void rel_precompute_kernel(
    const unsigned short* __restrict__ kws,
    const unsigned short* __restrict__ vws,
    const float* __restrict__ rel_att, const float* __restrict__ rel_msg,
    const float* __restrict__ pe,
    unsigned short* __restrict__ ktil, unsigned short* __restrict__ vtil,
    int pix_base)
{
    const int z   = blockIdx.z;         // tau*5 + j
    const int tau = z / 5, j = z % 5;
    const int m   = blockIdx.y;
    const int t   = threadIdx.x;
    const int half = t >> 7;            // wave-uniform
    const int pl   = blockIdx.x * 128 + (t & 127);

    bool present = false;
#pragma unroll
    for (int l = 0; l < LAG; ++l) present = present || ((int)pe[l * 3 + 2] == tau);
    if (!present) return;
    if (pl >= CHUNK) return;
    const int pix = pix_base + pl;

    const int tyj = (int)pe[j * 3 + 2];
    const int e   = tau * NT + tyj;

    const float* __restrict__ W =
        (half ? rel_msg : rel_att) + ((long)(e * NHEAD + m) << 10);
    const unsigned short* __restrict__ src =
        (half ? vws : kws) + ((long)j * HW + pix) * CD + m * DH;
    unsigned short* __restrict__ dst =
        (half ? vtil : ktil) + ((long)z * CHUNK + pl) * CD + m * DH;

    float in[32];
#pragma unroll
    for (int c8 = 0; c8 < 4; ++c8) {
        uint4 u = *(const uint4*)(src + (c8 << 3));   // 8 bf16
        in[c8 * 8 + 0] = __uint_as_float(u.x << 16);
        in[c8 * 8 + 1] = __uint_as_float(u.x & 0xffff0000u);
        in[c8 * 8 + 2] = __uint_as_float(u.y << 16);
        in[c8 * 8 + 3] = __uint_as_float(u.y & 0xffff0000u);
        in[c8 * 8 + 4] = __uint_as_float(u.z << 16);
        in[c8 * 8 + 5] = __uint_as_float(u.z & 0xffff0000u);
        in[c8 * 8 + 6] = __uint_as_float(u.w << 16);
        in[c8 * 8 + 7] = __uint_as_float(u.w & 0xffff0000u);
    }

    float acc[32];
#pragma unroll
    for (int p = 0; p < 32; ++p) acc[p] = 0.f;

    if (half == 0) {
        // acc[p] = sum_q W[p][q] * in[q]
#pragma unroll
        for (int p = 0; p < 32; ++p) {
            float s = 0.f;
#pragma unroll
            for (int q = 0; q < 32; ++q) s = fmaf(W[p * 32 + q], in[q], s);
            acc[p] = s;
        }
    } else {
        // acc[c] = sum_p W[p][c] * in[p]
#pragma unroll
        for (int p = 0; p < 32; ++p) {
            const float ip = in[p];
#pragma unroll
            for (int c = 0; c < 32; ++c) acc[c] = fmaf(W[p * 32 + c], ip, acc[c]);
        }
    }

#pragma unroll
    for (int c8 = 0; c8 < 4; ++c8) {
        uint4 o;
        o.x = pack2(acc[c8 * 8 + 0], acc[c8 * 8 + 1]);
        o.y = pack2(acc[c8 * 8 + 2], acc[c8 * 8 + 3]);
        o.z = pack2(acc[c8 * 8 + 4], acc[c8 * 8 + 5]);
        o.w = pack2(acc[c8 * 8 + 6], acc[c8 * 8 + 7]);
        *(uint4*)(dst + (c8 << 3)) = o;
    }
}

// ---------------------------------------------------------------------------
// Kernel 2: per (pixel, head) attention from precomputed ktil/vtil (bf16).
// 256 threads/block; each 32-lane group owns one (pixel, head); lane = p/c.
// grid.x = CHUNK (exactly CHUNK*8*32/256). No LDS, static indexing only.
// ---------------------------------------------------------------------------
__global__ __launch_bounds__(256) void attn_light_kernel(
    const unsigned short* __restrict__ qws,   // [L][HW][256] bf16
    const unsigned short* __restrict__ ktil,  // [15][CHUNK][256] bf16
    const unsigned short* __restrict__ vtil,  // [15][CHUNK][256] bf16
    const int*   __restrict__ mask,           // [HW][L]
    const float* __restrict__ pe,
    unsigned short* __restrict__ aws,         // [HW][L][256] bf16
    int pix_base)
{
    const int gid  = blockIdx.x * 256 + threadIdx.x;
    const int lane = threadIdx.x & 31;
    const int grp  = gid >> 5;       // pl*8 + m
    const int m    = grp & 7;
    const int pl   = grp >> 3;
    const int pix  = pix_base + pl;

    int ty[LAG];
#pragma unroll
    for (int l = 0; l < LAG; ++l) ty[l] = (int)pe[l * 3 + 2];
    bool p0 = false, p1 = false, p2 = false;
#pragma unroll
    for (int l = 0; l < LAG; ++l) {
        p0 = p0 || (ty[l] == 0); p1 = p1 || (ty[l] == 1); p2 = p2 || (ty[l] == 2);
    }

    const long PL    = (long)HW * CD;
    const long CPL   = (long)CHUNK * CD;
    const long baseg = (long)pix * CD + m * DH + lane;   // within one q plane
    const long basel = (long)pl  * CD + m * DH + lane;   // within one til plane

    float qv[LAG];
#pragma unroll
    for (int i = 0; i < LAG; ++i) qv[i] = bfu(qws[(long)i * PL + baseg]);

    float kt0[LAG], kt1[LAG], kt2[LAG];
#pragma unroll
    for (int j = 0; j < LAG; ++j) {
        kt0[j] = p0 ? bfu(ktil[(long)(0 * LAG + j) * CPL + basel]) : 0.f;
        kt1[j] = p1 ? bfu(ktil[(long)(1 * LAG + j) * CPL + basel]) : 0.f;
        kt2[j] = p2 ? bfu(ktil[(long)(2 * LAG + j) * CPL + basel]) : 0.f;
    }

    int mk[LAG];
#pragma unroll
    for (int j = 0; j < LAG; ++j) mk[j] = mask[pix * LAG + j];

    const float scale = 0.17677669529663687f;  // 32^-0.5
    float att[LAG][LAG];
#pragma unroll
    for (int i = 0; i < LAG; ++i) {
        const int tyi = ty[i];
#pragma unroll
        for (int j = 0; j < LAG; ++j) {
            float kt = (tyi == 0) ? kt0[j] : ((tyi == 1) ? kt1[j] : kt2[j]);
            float part = qv[i] * kt;
#pragma unroll
            for (int o = 16; o > 0; o >>= 1) part += __shfl_xor(part, o, 32);
            att[i][j] = part * scale;
        }
    }

#pragma unroll
    for (int i = 0; i < LAG; ++i) {
        float mx = -INFINITY;
#pragma unroll
        for (int j = 0; j < LAG; ++j) {
            att[i][j] = mk[j] ? att[i][j] : -INFINITY;
            mx = fmaxf(mx, att[i][j]);
        }
        float s = 0.f;
#pragma unroll
        for (int j = 0; j < LAG; ++j) {
            att[i][j] = __expf(att[i][j] - mx);
            s += att[i][j];
        }
        float inv = 1.f / s;
#pragma unroll
        for (int j = 0; j < LAG; ++j) att[i][j] *= inv;
    }

    float vt0[LAG], vt1[LAG], vt2[LAG];
#pragma unroll
    for (int j = 0; j < LAG; ++j) {
        vt0[j] = p0 ? bfu(vtil[(long)(0 * LAG + j) * CPL + basel]) : 0.f;
        vt1[j] = p1 ? bfu(vtil[(long)(1 * LAG + j) * CPL + basel]) : 0.f;
        vt2[j] = p2 ? bfu(vtil[(long)(2 * LAG + j) * CPL + basel]) : 0.f;
    }

#pragma unroll
    for (int i = 0; i < LAG; ++i) {
        const int tyi = ty[i];
        float acc = 0.f;
#pragma unroll
        for (int j = 0; j < LAG; ++j) {
            float mv = (tyi == 0) ? vt0[j] : ((tyi == 1) ? vt1[j] : vt2[j]);
            acc = fmaf(att[i][j], mv, acc);
        }
        aws[((long)pix * LAG + i) * CD + m * DH + lane] = (unsigned short)f2bf(acc);
    }
}

// ---------------------------------------------------------------------------
extern "C" void kernel_launch(void* const* d_in, const int* in_sizes, int n_in,
                              void* d_out, int out_size, void* d_ws, size_t ws_size,
                              hipStream_t stream) {
    const float* x    = (const float*)d_in[0];
    const int*   mask = (const int*)  d_in[1];
    const float* pe   = (const float*)d_in[2];
    const float* Wq   = (const float*)d_in[3];
    const float* bq   = (const float*)d_in[4];
    const float* Wk   = (const float*)d_in[5];
    const float* bk   = (const float*)d_in[6];
    const float* Wv   = (const float*)d_in[7];
    const float* bv   = (const float*)d_in[8];
    const float* Wa   = (const float*)d_in[9];
    const float* ba   = (const float*)d_in[10];
    const float* ratt = (const float*)d_in[11];
    const float* rmsg = (const float*)d_in[12];
    float* out = (float*)d_out;

    const size_t PLANE = (size_t)LAG * HW * CD;       // 22,528,000 bf16 elems
    const size_t TCH   = (size_t)NT * LAG * CHUNK * CD;  // 16,896,000 bf16 elems

    unsigned short* qws  = (unsigned short*)d_ws;
    unsigned short* kws  = qws + PLANE;
    unsigned short* vws  = kws + PLANE;
    unsigned short* aws  = vws + PLANE;
    unsigned short* ktil = aws + PLANE;
    unsigned short* vtil = ktil + TCH;
    // total: (4*PLANE + 2*TCH) * 2B ~= 248 MB

    dim3 g1(HW / 64, 4, LAG * 3);
    gemm_qkv_kernel<<<g1, 256, 0, stream>>>(x, pe, Wq, bq, Wk, bk, Wv, bv,
                                            qws, kws, vws);

    for (int c = 0; c < NCHUNK; ++c) {
        dim3 gp((CHUNK + 127) / 128, NHEAD, NT * LAG);
        rel_precompute_kernel<<<gp, 256, 0, stream>>>(kws, vws, ratt, rmsg, pe,
                                                      ktil, vtil, c * CHUNK);
        dim3 ga(CHUNK);
        attn_light_kernel<<<ga, 256, 0, stream>>>(qws, ktil, vtil, mask, pe,
                                                  aws, c * CHUNK);
    }

    dim3 g3(HW / 64, 4, LAG);
    gemm_out_kernel<<<g3, 256, 0, stream>>>(aws, pe, Wa, ba, out);
}

// Round 4
// 944.904 us; speedup vs baseline: 6.3141x; 1.5070x over previous
//
#include <hip/hip_runtime.h>
#include <math.h>

#define HW     17600   // 100*176 pixels
#define CD     256     // channels == D
#define LAG    5       // agents
#define NHEAD  8
#define DH     32
#define NT     3       // agent types
#define CHUNK  8800    // HW/2 pixel chunk for ktil/vtil staging
#define NCHUNK 2

typedef short bf16x8 __attribute__((ext_vector_type(8)));
typedef float f32x4  __attribute__((ext_vector_type(4)));

// ---- bf16 helpers ----------------------------------------------------------
__device__ __forceinline__ float bflo(unsigned u) { return __uint_as_float(u << 16); }
__device__ __forceinline__ float bfhi(unsigned u) { return __uint_as_float(u & 0xffff0000u); }
__device__ __forceinline__ unsigned f2bf(float f) {
    unsigned u = __float_as_uint(f);
    return (u + 0x7fffu + ((u >> 16) & 1u)) >> 16;   // RNE
}
__device__ __forceinline__ unsigned pack2(float a, float b) {
    return f2bf(a) | (f2bf(b) << 16);
}

// ---------------------------------------------------------------------------
// convert_w: W[k][n] fp32 -> Wt[n][k] bf16, 12 matrices (q0..2,k0..2,v0..2,a0..2)
// grid (16, 12), block 256. LDS 64x65 tile transpose.
// ---------------------------------------------------------------------------
__global__ __launch_bounds__(256) void convert_w_kernel(
    const float* __restrict__ Wq, const float* __restrict__ Wk,
    const float* __restrict__ Wv, const float* __restrict__ Wa,
    unsigned short* __restrict__ Wt)
{
    __shared__ float tile[64][65];
    const int mat = blockIdx.y;
    const int k0 = (blockIdx.x >> 2) * 64;
    const int n0 = (blockIdx.x & 3) * 64;
    const float* W;
    if      (mat < 3) W = Wq + (long)mat * 65536;
    else if (mat < 6) W = Wk + (long)(mat - 3) * 65536;
    else if (mat < 9) W = Wv + (long)(mat - 6) * 65536;
    else              W = Wa + (long)(mat - 9) * 65536;
    const int t = threadIdx.x;
#pragma unroll
    for (int r = 0; r < 16; ++r) {
        int idx = r * 256 + t;
        int row = idx >> 6, col = idx & 63;
        tile[row][col] = W[(long)(k0 + row) * 256 + n0 + col];
    }
    __syncthreads();
    unsigned short* dst = Wt + (long)mat * 65536;
#pragma unroll
    for (int r = 0; r < 16; ++r) {
        int idx = r * 256 + t;
        int row = idx >> 6, col = idx & 63;
        dst[(long)(n0 + row) * 256 + k0 + col] = (unsigned short)f2bf(tile[col][row]);
    }
}

// ---------------------------------------------------------------------------
// MFMA GEMM core: Y[64 x 256] = A[M x 256] @ Wt^T + bias.
// Wt is [256 n][256 k] bf16. A fp32 (converted in staging) or bf16.
// block = 256 (4 waves, 2x2 of 32x128 sub-tiles), grid.x = M/64.
// mfma_f32_16x16x32_bf16; frag layouts per m89/m91-verified mapping.
// ---------------------------------------------------------------------------
template<bool AF32, bool YBF>
__device__ __forceinline__ void gemm_mfma_core(
    const void* __restrict__ Aptr, long lda,
    const unsigned short* __restrict__ Wt,
    const float* __restrict__ bias,
    void* __restrict__ Yptr, long ldy)
{
    __shared__ unsigned short As[64][72];    // 64 m x 64 k, pad->72 (144B rows)
    __shared__ unsigned short Ws[256][72];   // 256 n x 64 k

    const int t  = threadIdx.x;
    const int m0 = blockIdx.x * 64;
    const int w  = t >> 6;
    const int l  = t & 63;
    const int wr = w >> 1;          // rows wr*32
    const int wc = w & 1;           // cols wc*128
    const int fr = l & 15;
    const int ko = (l >> 4) << 3;   // k-octet: 0,8,16,24

    f32x4 acc[2][8];
#pragma unroll
    for (int i = 0; i < 2; ++i)
#pragma unroll
        for (int j = 0; j < 8; ++j) {
            acc[i][j][0] = 0.f; acc[i][j][1] = 0.f;
            acc[i][j][2] = 0.f; acc[i][j][3] = 0.f;
        }

    for (int ks = 0; ks < 4; ++ks) {
        const int k0 = ks << 6;
        __syncthreads();
        // stage A: 64x64 elems, 2 rounds of 256 thr x 8 bf16
#pragma unroll
        for (int r = 0; r < 2; ++r) {
            int idx = (r << 11) + (t << 3);
            int row = idx >> 6, col = idx & 63;
            if (AF32) {
                const float* src = (const float*)Aptr + (long)(m0 + row) * lda + k0 + col;
                float4 f0 = *(const float4*)src;
                float4 f1 = *(const float4*)(src + 4);
                uint4 u;
                u.x = pack2(f0.x, f0.y); u.y = pack2(f0.z, f0.w);
                u.z = pack2(f1.x, f1.y); u.w = pack2(f1.z, f1.w);
                *(uint4*)(&As[row][col]) = u;
            } else {
                const unsigned short* src =
                    (const unsigned short*)Aptr + (long)(m0 + row) * lda + k0 + col;
                *(uint4*)(&As[row][col]) = *(const uint4*)src;
            }
        }
        // stage Wt: 256x64 elems, 8 rounds
#pragma unroll
        for (int r = 0; r < 8; ++r) {
            int idx = (r << 11) + (t << 3);
            int row = idx >> 6, col = idx & 63;
            *(uint4*)(&Ws[row][col]) = *(const uint4*)(Wt + (long)row * 256 + k0 + col);
        }
        __syncthreads();
#pragma unroll
        for (int kk = 0; kk < 2; ++kk) {
            bf16x8 a[2], b[8];
#pragma unroll
            for (int i = 0; i < 2; ++i)
                a[i] = *(const bf16x8*)(&As[wr * 32 + i * 16 + fr][(kk << 5) + ko]);
#pragma unroll
            for (int j = 0; j < 8; ++j)
                b[j] = *(const bf16x8*)(&Ws[wc * 128 + j * 16 + fr][(kk << 5) + ko]);
#pragma unroll
            for (int i = 0; i < 2; ++i)
#pragma unroll
                for (int j = 0; j < 8; ++j)
                    acc[i][j] = __builtin_amdgcn_mfma_f32_16x16x32_bf16(
                        a[i], b[j], acc[i][j], 0, 0, 0);
        }
    }

    const int fq = l >> 4;
#pragma unroll
    for (int j = 0; j < 8; ++j) {
        int col = wc * 128 + j * 16 + fr;
        float bz = bias[col];
#pragma unroll
        for (int i = 0; i < 2; ++i) {
            int rowb = m0 + wr * 32 + i * 16 + (fq << 2);
#pragma unroll
            for (int e = 0; e < 4; ++e) {
                float v = acc[i][j][e] + bz;
                if (YBF)
                    ((unsigned short*)Yptr)[(long)(rowb + e) * ldy + col] =
                        (unsigned short)f2bf(v);
                else
                    ((float*)Yptr)[(long)(rowb + e) * ldy + col] = v;
            }
        }
    }
}

// ---------------------------------------------------------------------------
// Kernel 1: q/k/v projections. grid (275, 1, 15): z = l*3 + proj
// ---------------------------------------------------------------------------
__global__ __launch_bounds__(256) void gemm_qkv_mfma(
    const float* __restrict__ x, const float* __restrict__ pe,
    const unsigned short* __restrict__ Wt,
    const float* __restrict__ bq, const float* __restrict__ bk,
    const float* __restrict__ bv,
    unsigned short* __restrict__ qws, unsigned short* __restrict__ kws,
    unsigned short* __restrict__ vws)
{
    const int z = blockIdx.z;
    const int lag = z / 3, proj = z % 3;
    const int tpe = (int)pe[lag * 3 + 2];
    const float* A = x + (long)lag * HW * CD;
    const unsigned short* Wm = Wt + (long)(proj * 3 + tpe) * 65536;
    const float* bias;
    unsigned short* Y;
    if      (proj == 0) { bias = bq; Y = qws; }
    else if (proj == 1) { bias = bk; Y = kws; }
    else                { bias = bv; Y = vws; }
    bias += tpe * CD;
    Y += (long)lag * HW * CD;
    gemm_mfma_core<true, true>(A, CD, Wm, bias, Y, CD);
}

// ---------------------------------------------------------------------------
// Kernel 4: output projection. grid (275, 1, 5).
// ---------------------------------------------------------------------------
__global__ __launch_bounds__(256) void gemm_out_mfma(
    const unsigned short* __restrict__ aws, const float* __restrict__ pe,
    const unsigned short* __restrict__ Wt, const float* __restrict__ ba,
    float* __restrict__ out)
{
    const int lag = blockIdx.z;
    const int tpe = (int)pe[lag * 3 + 2];
    const unsigned short* A = aws + (long)lag * CD;   // row stride 1280
    const unsigned short* Wm = Wt + (long)(9 + tpe) * 65536;
    const float* bias = ba + tpe * CD;
    float* Y = out + (long)lag * HW * CD;
    gemm_mfma_core<false, false>(A, (long)LAG * CD, Wm, bias, Y, CD);
}

// ---------------------------------------------------------------------------
// Kernel 2: relational precompute; k/v read ONCE, loop 3 taus in-thread.
//   ktil[tau*5+j] = Watt[tau*3+ty_j][m] . k_j   (per head m, per pixel)
//   vtil[tau*5+j][c] = sum_p Wmsg[tau*3+ty_j][m][p][c] v_j[p]
// grid (ceil(CHUNK/128), 8, 5); block 256: waves 0-1 -> ktil, waves 2-3 -> vtil
// ---------------------------------------------------------------------------
__global__ __launch_bounds__(256) void rel_precompute_kernel(
    const unsigned short* __restrict__ kws, const unsigned short* __restrict__ vws,
    const float* __restrict__ rel_att, const float* __restrict__ rel_msg,
    const float* __restrict__ pe,
    unsigned short* __restrict__ ktil, unsigned short* __restrict__ vtil,
    int pix_base)
{
    const int j = blockIdx.z;
    const int m = blockIdx.y;
    const int t = threadIdx.x;
    const int half = t >> 7;                 // wave-uniform
    const int pl = blockIdx.x * 128 + (t & 127);
    if (pl >= CHUNK) return;
    const int pix = pix_base + pl;

    int ty[LAG];
#pragma unroll
    for (int i = 0; i < LAG; ++i) ty[i] = (int)pe[i * 3 + 2];
    bool pres[NT] = {false, false, false};
#pragma unroll
    for (int i = 0; i < LAG; ++i) {
        pres[0] = pres[0] || (ty[i] == 0);
        pres[1] = pres[1] || (ty[i] == 1);
        pres[2] = pres[2] || (ty[i] == 2);
    }
    const int tyj = ty[j];

    const unsigned short* src =
        (half ? vws : kws) + ((long)j * HW + pix) * CD + m * DH;
    float in[32];
#pragma unroll
    for (int c = 0; c < 4; ++c) {
        uint4 u = *(const uint4*)(src + (c << 3));
        in[c*8+0] = bflo(u.x); in[c*8+1] = bfhi(u.x);
        in[c*8+2] = bflo(u.y); in[c*8+3] = bfhi(u.y);
        in[c*8+4] = bflo(u.z); in[c*8+5] = bfhi(u.z);
        in[c*8+6] = bflo(u.w); in[c*8+7] = bfhi(u.w);
    }

    const float* Wb = half ? rel_msg : rel_att;
    unsigned short* dstb = half ? vtil : ktil;

#pragma unroll
    for (int tau = 0; tau < NT; ++tau) {
        if (!pres[tau]) continue;
        const float* W = Wb + ((long)((tau * NT + tyj) * NHEAD + m) << 10);
        float acc[32];
        if (half == 0) {
#pragma unroll
            for (int p = 0; p < 32; ++p) {
                float s = 0.f;
#pragma unroll
                for (int q = 0; q < 32; ++q) s = fmaf(W[p * 32 + q], in[q], s);
                acc[p] = s;
            }
        } else {
#pragma unroll
            for (int c = 0; c < 32; ++c) acc[c] = 0.f;
#pragma unroll
            for (int p = 0; p < 32; ++p) {
                const float ip = in[p];
#pragma unroll
                for (int c = 0; c < 32; ++c) acc[c] = fmaf(W[p * 32 + c], ip, acc[c]);
            }
        }
        unsigned short* dst = dstb + ((long)(tau * LAG + j) * CHUNK + pl) * CD + m * DH;
#pragma unroll
        for (int c = 0; c < 4; ++c) {
            uint4 o;
            o.x = pack2(acc[c*8+0], acc[c*8+1]);
            o.y = pack2(acc[c*8+2], acc[c*8+3]);
            o.z = pack2(acc[c*8+4], acc[c*8+5]);
            o.w = pack2(acc[c*8+6], acc[c*8+7]);
            *(uint4*)(dst + (c << 3)) = o;
        }
    }
}

// ---------------------------------------------------------------------------
// Kernel 3: attention. 4-lane groups own (pixel, head); each lane holds 8 dims.
// All loads uint4 (16B/lane). grid.x = CHUNK*32/256 = 1100, block 256.
// ---------------------------------------------------------------------------
__global__ __launch_bounds__(256) void attn_light_kernel(
    const unsigned short* __restrict__ qws,
    const unsigned short* __restrict__ ktil,
    const unsigned short* __restrict__ vtil,
    const int* __restrict__ mask, const float* __restrict__ pe,
    unsigned short* __restrict__ aws, int pix_base)
{
    const int t = threadIdx.x;
    const int gid = blockIdx.x * 256 + t;
    const int o = gid & 3;          // dim octet
    const int grp = gid >> 2;       // pl*8 + m
    const int m = grp & 7;
    const int pl = grp >> 3;
    const int pix = pix_base + pl;

    int ty[LAG];
#pragma unroll
    for (int i = 0; i < LAG; ++i) ty[i] = (int)pe[i * 3 + 2];
    bool p0 = false, p1 = false, p2 = false;
#pragma unroll
    for (int i = 0; i < LAG; ++i) {
        p0 = p0 || (ty[i] == 0); p1 = p1 || (ty[i] == 1); p2 = p2 || (ty[i] == 2);
    }

    const long PL = (long)HW * CD;
    const long CPL = (long)CHUNK * CD;
    const long baseg = (long)pix * CD + m * DH + o * 8;
    const long basel = (long)pl * CD + m * DH + o * 8;

    float qf[LAG][8];
#pragma unroll
    for (int i = 0; i < LAG; ++i) {
        uint4 u = *(const uint4*)(qws + (long)i * PL + baseg);
        qf[i][0] = bflo(u.x); qf[i][1] = bfhi(u.x);
        qf[i][2] = bflo(u.y); qf[i][3] = bfhi(u.y);
        qf[i][4] = bflo(u.z); qf[i][5] = bfhi(u.z);
        qf[i][6] = bflo(u.w); qf[i][7] = bfhi(u.w);
    }

    const uint4 z4 = make_uint4(0, 0, 0, 0);
    uint4 kt0[LAG], kt1[LAG], kt2[LAG];
#pragma unroll
    for (int j = 0; j < LAG; ++j) {
        kt0[j] = p0 ? *(const uint4*)(ktil + (long)(0 * LAG + j) * CPL + basel) : z4;
        kt1[j] = p1 ? *(const uint4*)(ktil + (long)(1 * LAG + j) * CPL + basel) : z4;
        kt2[j] = p2 ? *(const uint4*)(ktil + (long)(2 * LAG + j) * CPL + basel) : z4;
    }

    int mk[LAG];
#pragma unroll
    for (int j = 0; j < LAG; ++j) mk[j] = mask[pix * LAG + j];

    const float scale = 0.17677669529663687f;  // 32^-0.5
    float att[LAG][LAG];
#pragma unroll
    for (int i = 0; i < LAG; ++i) {
        const int tyi = ty[i];
#pragma unroll
        for (int j = 0; j < LAG; ++j) {
            uint4 s = (tyi == 0) ? kt0[j] : ((tyi == 1) ? kt1[j] : kt2[j]);
            float part;
            part = qf[i][0] * bflo(s.x);
            part = fmaf(qf[i][1], bfhi(s.x), part);
            part = fmaf(qf[i][2], bflo(s.y), part);
            part = fmaf(qf[i][3], bfhi(s.y), part);
            part = fmaf(qf[i][4], bflo(s.z), part);
            part = fmaf(qf[i][5], bfhi(s.z), part);
            part = fmaf(qf[i][6], bflo(s.w), part);
            part = fmaf(qf[i][7], bfhi(s.w), part);
            part += __shfl_xor(part, 1);
            part += __shfl_xor(part, 2);
            att[i][j] = part * scale;
        }
    }

#pragma unroll
    for (int i = 0; i < LAG; ++i) {
        float mx = -INFINITY;
#pragma unroll
        for (int j = 0; j < LAG; ++j) {
            att[i][j] = mk[j] ? att[i][j] : -INFINITY;
            mx = fmaxf(mx, att[i][j]);
        }
        float ssum = 0.f;
#pragma unroll
        for (int j = 0; j < LAG; ++j) {
            att[i][j] = __expf(att[i][j] - mx);
            ssum += att[i][j];
        }
        float inv = 1.f / ssum;
#pragma unroll
        for (int j = 0; j < LAG; ++j) att[i][j] *= inv;
    }

    uint4 vt0[LAG], vt1[LAG], vt2[LAG];
#pragma unroll
    for (int j = 0; j < LAG; ++j) {
        vt0[j] = p0 ? *(const uint4*)(vtil + (long)(0 * LAG + j) * CPL + basel) : z4;
        vt1[j] = p1 ? *(const uint4*)(vtil + (long)(1 * LAG + j) * CPL + basel) : z4;
        vt2[j] = p2 ? *(const uint4*)(vtil + (long)(2 * LAG + j) * CPL + basel) : z4;
    }

#pragma unroll
    for (int i = 0; i < LAG; ++i) {
        const int tyi = ty[i];
        float af[8] = {0.f, 0.f, 0.f, 0.f, 0.f, 0.f, 0.f, 0.f};
#pragma unroll
        for (int j = 0; j < LAG; ++j) {
            uint4 s = (tyi == 0) ? vt0[j] : ((tyi == 1) ? vt1[j] : vt2[j]);
            float wj = att[i][j];
            af[0] = fmaf(wj, bflo(s.x), af[0]); af[1] = fmaf(wj, bfhi(s.x), af[1]);
            af[2] = fmaf(wj, bflo(s.y), af[2]); af[3] = fmaf(wj, bfhi(s.y), af[3]);
            af[4] = fmaf(wj, bflo(s.z), af[4]); af[5] = fmaf(wj, bfhi(s.z), af[5]);
            af[6] = fmaf(wj, bflo(s.w), af[6]); af[7] = fmaf(wj, bfhi(s.w), af[7]);
        }
        uint4 ov;
        ov.x = pack2(af[0], af[1]); ov.y = pack2(af[2], af[3]);
        ov.z = pack2(af[4], af[5]); ov.w = pack2(af[6], af[7]);
        *(uint4*)(aws + ((long)pix * LAG + i) * CD + m * DH + o * 8) = ov;
    }
}

// ---------------------------------------------------------------------------
extern "C" void kernel_launch(void* const* d_in, const int* in_sizes, int n_in,
                              void* d_out, int out_size, void* d_ws, size_t ws_size,
                              hipStream_t stream) {
    const float* x    = (const float*)d_in[0];
    const int*   mask = (const int*)  d_in[1];
    const float* pe   = (const float*)d_in[2];
    const float* Wq   = (const float*)d_in[3];
    const float* bq   = (const float*)d_in[4];
    const float* Wk   = (const float*)d_in[5];
    const float* bk   = (const float*)d_in[6];
    const float* Wv   = (const float*)d_in[7];
    const float* bv   = (const float*)d_in[8];
    const float* Wa   = (const float*)d_in[9];
    const float* ba   = (const float*)d_in[10];
    const float* ratt = (const float*)d_in[11];
    const float* rmsg = (const float*)d_in[12];
    float* out = (float*)d_out;

    const size_t PLANE = (size_t)LAG * HW * CD;          // 22,528,000 elems
    const size_t TCH   = (size_t)NT * LAG * CHUNK * CD;  // 33,792,000 elems

    unsigned short* qws  = (unsigned short*)d_ws;
    unsigned short* kws  = qws + PLANE;
    unsigned short* vws  = kws + PLANE;
    unsigned short* aws  = vws + PLANE;
    unsigned short* ktil = aws + PLANE;
    unsigned short* vtil = ktil + TCH;
    unsigned short* Wt   = vtil + TCH;    // 786,432 elems
    // total ~317 MB

    convert_w_kernel<<<dim3(16, 12), 256, 0, stream>>>(Wq, Wk, Wv, Wa, Wt);

    gemm_qkv_mfma<<<dim3(HW / 64, 1, LAG * 3), 256, 0, stream>>>(
        x, pe, Wt, bq, bk, bv, qws, kws, vws);

    for (int c = 0; c < NCHUNK; ++c) {
        rel_precompute_kernel<<<dim3((CHUNK + 127) / 128, NHEAD, LAG), 256, 0, stream>>>(
            kws, vws, ratt, rmsg, pe, ktil, vtil, c * CHUNK);
        attn_light_kernel<<<dim3(CHUNK * 32 / 256), 256, 0, stream>>>(
            qws, ktil, vtil, mask, pe, aws, c * CHUNK);
    }

    gemm_out_mfma<<<dim3(HW / 64, 1, LAG), 256, 0, stream>>>(aws, pe, Wt, ba, out);
}

// Round 5
// 555.849 us; speedup vs baseline: 10.7336x; 1.6999x over previous
//
#include <hip/hip_runtime.h>
#include <math.h>

#define HW     17600   // 100*176 pixels
#define CD     256     // channels == D
#define LAG    5       // agents
#define NHEAD  8
#define DH     32
#define NT     3       // agent types
#define CHUNKMAX 8832  // buffer stride (pixels); chunks are 8832 + 8768

typedef short bf16x8 __attribute__((ext_vector_type(8)));
typedef float f32x4  __attribute__((ext_vector_type(4)));

// ---- bf16 helpers ----------------------------------------------------------
__device__ __forceinline__ float bflo(unsigned u) { return __uint_as_float(u << 16); }
__device__ __forceinline__ float bfhi(unsigned u) { return __uint_as_float(u & 0xffff0000u); }
__device__ __forceinline__ unsigned f2bf(float f) {
    unsigned u = __float_as_uint(f);
    return (u + 0x7fffu + ((u >> 16) & 1u)) >> 16;   // RNE
}
__device__ __forceinline__ unsigned pack2(float a, float b) {
    return f2bf(a) | (f2bf(b) << 16);
}

// ---------------------------------------------------------------------------
// convert_w: W[k][n] fp32 -> Wt[n][k] bf16, 12 matrices (q0..2,k0..2,v0..2,a0..2)
// grid (16, 12), block 256. LDS 64x65 tile transpose.
// ---------------------------------------------------------------------------
__global__ __launch_bounds__(256) void convert_w_kernel(
    const float* __restrict__ Wq, const float* __restrict__ Wk,
    const float* __restrict__ Wv, const float* __restrict__ Wa,
    unsigned short* __restrict__ Wt)
{
    __shared__ float tile[64][65];
    const int mat = blockIdx.y;
    const int k0 = (blockIdx.x >> 2) * 64;
    const int n0 = (blockIdx.x & 3) * 64;
    const float* W;
    if      (mat < 3) W = Wq + (long)mat * 65536;
    else if (mat < 6) W = Wk + (long)(mat - 3) * 65536;
    else if (mat < 9) W = Wv + (long)(mat - 6) * 65536;
    else              W = Wa + (long)(mat - 9) * 65536;
    const int t = threadIdx.x;
#pragma unroll
    for (int r = 0; r < 16; ++r) {
        int idx = r * 256 + t;
        int row = idx >> 6, col = idx & 63;
        tile[row][col] = W[(long)(k0 + row) * 256 + n0 + col];
    }
    __syncthreads();
    unsigned short* dst = Wt + (long)mat * 65536;
#pragma unroll
    for (int r = 0; r < 16; ++r) {
        int idx = r * 256 + t;
        int row = idx >> 6, col = idx & 63;
        dst[(long)(n0 + row) * 256 + k0 + col] = (unsigned short)f2bf(tile[col][row]);
    }
}

// ---------------------------------------------------------------------------
// convert_rel: rel_att -> rattB bf16 [9][8][32 p][32 q] (plain cast),
//              rel_msg -> rmsgT bf16 [9][8][32 c][32 p] (transposed).
// grid (9, 8), block 256; 4 elems/thread.
// ---------------------------------------------------------------------------
__global__ __launch_bounds__(256) void convert_rel_kernel(
    const float* __restrict__ rel_att, const float* __restrict__ rel_msg,
    unsigned short* __restrict__ rattB, unsigned short* __restrict__ rmsgT)
{
    const long base = ((long)(blockIdx.x * NHEAD + blockIdx.y)) << 10;
    const int t = threadIdx.x;
#pragma unroll
    for (int i = 0; i < 4; ++i) {
        int idx = t * 4 + i;            // p*32+q
        int p = idx >> 5, q = idx & 31;
        rattB[base + idx] = (unsigned short)f2bf(rel_att[base + idx]);
        rmsgT[base + q * 32 + p] = (unsigned short)f2bf(rel_msg[base + idx]);
    }
}

// ---------------------------------------------------------------------------
// MFMA GEMM core: Y[64 x 256] = A[M x 256] @ Wt^T + bias.
// ---------------------------------------------------------------------------
template<bool AF32, bool YBF>
__device__ __forceinline__ void gemm_mfma_core(
    const void* __restrict__ Aptr, long lda,
    const unsigned short* __restrict__ Wt,
    const float* __restrict__ bias,
    void* __restrict__ Yptr, long ldy)
{
    __shared__ unsigned short As[64][72];
    __shared__ unsigned short Ws[256][72];

    const int t  = threadIdx.x;
    const int m0 = blockIdx.x * 64;
    const int w  = t >> 6;
    const int l  = t & 63;
    const int wr = w >> 1;
    const int wc = w & 1;
    const int fr = l & 15;
    const int ko = (l >> 4) << 3;

    f32x4 acc[2][8];
#pragma unroll
    for (int i = 0; i < 2; ++i)
#pragma unroll
        for (int j = 0; j < 8; ++j) {
            acc[i][j][0] = 0.f; acc[i][j][1] = 0.f;
            acc[i][j][2] = 0.f; acc[i][j][3] = 0.f;
        }

    for (int ks = 0; ks < 4; ++ks) {
        const int k0 = ks << 6;
        __syncthreads();
#pragma unroll
        for (int r = 0; r < 2; ++r) {
            int idx = (r << 11) + (t << 3);
            int row = idx >> 6, col = idx & 63;
            if (AF32) {
                const float* src = (const float*)Aptr + (long)(m0 + row) * lda + k0 + col;
                float4 f0 = *(const float4*)src;
                float4 f1 = *(const float4*)(src + 4);
                uint4 u;
                u.x = pack2(f0.x, f0.y); u.y = pack2(f0.z, f0.w);
                u.z = pack2(f1.x, f1.y); u.w = pack2(f1.z, f1.w);
                *(uint4*)(&As[row][col]) = u;
            } else {
                const unsigned short* src =
                    (const unsigned short*)Aptr + (long)(m0 + row) * lda + k0 + col;
                *(uint4*)(&As[row][col]) = *(const uint4*)src;
            }
        }
#pragma unroll
        for (int r = 0; r < 8; ++r) {
            int idx = (r << 11) + (t << 3);
            int row = idx >> 6, col = idx & 63;
            *(uint4*)(&Ws[row][col]) = *(const uint4*)(Wt + (long)row * 256 + k0 + col);
        }
        __syncthreads();
#pragma unroll
        for (int kk = 0; kk < 2; ++kk) {
            bf16x8 a[2], b[8];
#pragma unroll
            for (int i = 0; i < 2; ++i)
                a[i] = *(const bf16x8*)(&As[wr * 32 + i * 16 + fr][(kk << 5) + ko]);
#pragma unroll
            for (int j = 0; j < 8; ++j)
                b[j] = *(const bf16x8*)(&Ws[wc * 128 + j * 16 + fr][(kk << 5) + ko]);
#pragma unroll
            for (int i = 0; i < 2; ++i)
#pragma unroll
                for (int j = 0; j < 8; ++j)
                    acc[i][j] = __builtin_amdgcn_mfma_f32_16x16x32_bf16(
                        a[i], b[j], acc[i][j], 0, 0, 0);
        }
    }

    const int fq = l >> 4;
#pragma unroll
    for (int j = 0; j < 8; ++j) {
        int col = wc * 128 + j * 16 + fr;
        float bz = bias[col];
#pragma unroll
        for (int i = 0; i < 2; ++i) {
            int rowb = m0 + wr * 32 + i * 16 + (fq << 2);
#pragma unroll
            for (int e = 0; e < 4; ++e) {
                float v = acc[i][j][e] + bz;
                if (YBF)
                    ((unsigned short*)Yptr)[(long)(rowb + e) * ldy + col] =
                        (unsigned short)f2bf(v);
                else
                    ((float*)Yptr)[(long)(rowb + e) * ldy + col] = v;
            }
        }
    }
}

// ---------------------------------------------------------------------------
// Kernel 1: q/k/v projections. grid (275, 1, 15)
// ---------------------------------------------------------------------------
__global__ __launch_bounds__(256) void gemm_qkv_mfma(
    const float* __restrict__ x, const float* __restrict__ pe,
    const unsigned short* __restrict__ Wt,
    const float* __restrict__ bq, const float* __restrict__ bk,
    const float* __restrict__ bv,
    unsigned short* __restrict__ qws, unsigned short* __restrict__ kws,
    unsigned short* __restrict__ vws)
{
    const int z = blockIdx.z;
    const int lag = z / 3, proj = z % 3;
    const int tpe = (int)pe[lag * 3 + 2];
    const float* A = x + (long)lag * HW * CD;
    const unsigned short* Wm = Wt + (long)(proj * 3 + tpe) * 65536;
    const float* bias;
    unsigned short* Y;
    if      (proj == 0) { bias = bq; Y = qws; }
    else if (proj == 1) { bias = bk; Y = kws; }
    else                { bias = bv; Y = vws; }
    bias += tpe * CD;
    Y += (long)lag * HW * CD;
    gemm_mfma_core<true, true>(A, CD, Wm, bias, Y, CD);
}

// ---------------------------------------------------------------------------
// Kernel 4: output projection. grid (275, 1, 5).
// ---------------------------------------------------------------------------
__global__ __launch_bounds__(256) void gemm_out_mfma(
    const unsigned short* __restrict__ aws, const float* __restrict__ pe,
    const unsigned short* __restrict__ Wt, const float* __restrict__ ba,
    float* __restrict__ out)
{
    const int lag = blockIdx.z;
    const int tpe = (int)pe[lag * 3 + 2];
    const unsigned short* A = aws + (long)lag * CD;
    const unsigned short* Wm = Wt + (long)(9 + tpe) * 65536;
    const float* bias = ba + tpe * CD;
    float* Y = out + (long)lag * HW * CD;
    gemm_mfma_core<false, false>(A, (long)LAG * CD, Wm, bias, Y, CD);
}

// ---------------------------------------------------------------------------
// Kernel 2: relational precompute via MFMA. K=32 GEMM per (tau, j, head).
//   ktil[tau*5+j][pl][m*32+p] = sum_q k[j][pix][m*32+q] * Watt[tau*3+tyj][m][p][q]
//   vtil[tau*5+j][pl][m*32+c] = sum_p v[j][pix][m*32+p] * Wmsg[tau*3+tyj][m][p][c]
// grid (chunk_len/64, 8, 5), block 256 = 4 waves; each wave owns 16 pixels.
// A-frag: lane row = pixel (l&15), k-octet = (l>>4)*8 -> one uint4 per lane.
// B-frag ktil: rattB[e][m] row p=(l&15)+16*ntile, q-octet contiguous.
// B-frag vtil: rmsgT[e][m] row c=(l&15)+16*ntile, p-octet contiguous.
// C: col = l&15 (p/c), row = (l>>4)*4+reg (pixel).
// ---------------------------------------------------------------------------
__global__ __launch_bounds__(256) void rel_precompute_mfma(
    const unsigned short* __restrict__ kws, const unsigned short* __restrict__ vws,
    const unsigned short* __restrict__ rattB, const unsigned short* __restrict__ rmsgT,
    const float* __restrict__ pe,
    unsigned short* __restrict__ ktil, unsigned short* __restrict__ vtil,
    int pix_base)
{
    const int j = blockIdx.z;
    const int m = blockIdx.y;
    const int t = threadIdx.x;
    const int w = t >> 6;
    const int l = t & 63;
    const int col = l & 15;          // pixel-in-16 (A/C row pairing differs; see frags)
    const int ko  = (l >> 4) << 3;   // k-octet

    int ty[LAG];
#pragma unroll
    for (int i = 0; i < LAG; ++i) ty[i] = (int)pe[i * 3 + 2];
    bool pres[NT] = {false, false, false};
#pragma unroll
    for (int i = 0; i < LAG; ++i) {
        pres[0] = pres[0] || (ty[i] == 0);
        pres[1] = pres[1] || (ty[i] == 1);
        pres[2] = pres[2] || (ty[i] == 2);
    }
    const int tyj = ty[j];

    const int pl0 = blockIdx.x * 64 + w * 16;
    const int pix = pix_base + pl0 + col;

    const long kvoff = ((long)j * HW + pix) * CD + m * DH + ko;
    bf16x8 Ak = *(const bf16x8*)(kws + kvoff);
    bf16x8 Av = *(const bf16x8*)(vws + kvoff);

    const int prow = (l >> 4) << 2;  // C row base (pixel-in-16)

#pragma unroll
    for (int tau = 0; tau < NT; ++tau) {
        if (!pres[tau]) continue;
        const int e = tau * NT + tyj;
        const unsigned short* bk = rattB + ((long)(e * NHEAD + m) << 10);
        const unsigned short* bv = rmsgT + ((long)(e * NHEAD + m) << 10);

        bf16x8 Bk0 = *(const bf16x8*)(bk + col * 32 + ko);
        bf16x8 Bk1 = *(const bf16x8*)(bk + (col + 16) * 32 + ko);
        bf16x8 Bv0 = *(const bf16x8*)(bv + col * 32 + ko);
        bf16x8 Bv1 = *(const bf16x8*)(bv + (col + 16) * 32 + ko);

        f32x4 z = {0.f, 0.f, 0.f, 0.f};
        f32x4 ck0 = __builtin_amdgcn_mfma_f32_16x16x32_bf16(Ak, Bk0, z, 0, 0, 0);
        f32x4 ck1 = __builtin_amdgcn_mfma_f32_16x16x32_bf16(Ak, Bk1, z, 0, 0, 0);
        f32x4 cv0 = __builtin_amdgcn_mfma_f32_16x16x32_bf16(Av, Bv0, z, 0, 0, 0);
        f32x4 cv1 = __builtin_amdgcn_mfma_f32_16x16x32_bf16(Av, Bv1, z, 0, 0, 0);

        unsigned short* dk = ktil + ((long)(tau * LAG + j) * CHUNKMAX) * CD + m * DH;
        unsigned short* dv = vtil + ((long)(tau * LAG + j) * CHUNKMAX) * CD + m * DH;
#pragma unroll
        for (int e4 = 0; e4 < 4; ++e4) {
            const long ob = (long)(pl0 + prow + e4) * CD;
            dk[ob + col]      = (unsigned short)f2bf(ck0[e4]);
            dk[ob + 16 + col] = (unsigned short)f2bf(ck1[e4]);
            dv[ob + col]      = (unsigned short)f2bf(cv0[e4]);
            dv[ob + 16 + col] = (unsigned short)f2bf(cv1[e4]);
        }
    }
}

// ---------------------------------------------------------------------------
// Kernel 3: attention. 4-lane groups own (pixel, head); each lane holds 8 dims.
// grid.x = chunk_len/8, block 256.
// ---------------------------------------------------------------------------
__global__ __launch_bounds__(256) void attn_light_kernel(
    const unsigned short* __restrict__ qws,
    const unsigned short* __restrict__ ktil,
    const unsigned short* __restrict__ vtil,
    const int* __restrict__ mask, const float* __restrict__ pe,
    unsigned short* __restrict__ aws, int pix_base)
{
    const int t = threadIdx.x;
    const int gid = blockIdx.x * 256 + t;
    const int o = gid & 3;
    const int grp = gid >> 2;
    const int m = grp & 7;
    const int pl = grp >> 3;
    const int pix = pix_base + pl;

    int ty[LAG];
#pragma unroll
    for (int i = 0; i < LAG; ++i) ty[i] = (int)pe[i * 3 + 2];
    bool p0 = false, p1 = false, p2 = false;
#pragma unroll
    for (int i = 0; i < LAG; ++i) {
        p0 = p0 || (ty[i] == 0); p1 = p1 || (ty[i] == 1); p2 = p2 || (ty[i] == 2);
    }

    const long PL = (long)HW * CD;
    const long CPL = (long)CHUNKMAX * CD;
    const long baseg = (long)pix * CD + m * DH + o * 8;
    const long basel = (long)pl * CD + m * DH + o * 8;

    float qf[LAG][8];
#pragma unroll
    for (int i = 0; i < LAG; ++i) {
        uint4 u = *(const uint4*)(qws + (long)i * PL + baseg);
        qf[i][0] = bflo(u.x); qf[i][1] = bfhi(u.x);
        qf[i][2] = bflo(u.y); qf[i][3] = bfhi(u.y);
        qf[i][4] = bflo(u.z); qf[i][5] = bfhi(u.z);
        qf[i][6] = bflo(u.w); qf[i][7] = bfhi(u.w);
    }

    const uint4 z4 = make_uint4(0, 0, 0, 0);
    uint4 kt0[LAG], kt1[LAG], kt2[LAG];
#pragma unroll
    for (int j = 0; j < LAG; ++j) {
        kt0[j] = p0 ? *(const uint4*)(ktil + (long)(0 * LAG + j) * CPL + basel) : z4;
        kt1[j] = p1 ? *(const uint4*)(ktil + (long)(1 * LAG + j) * CPL + basel) : z4;
        kt2[j] = p2 ? *(const uint4*)(ktil + (long)(2 * LAG + j) * CPL + basel) : z4;
    }

    int mk[LAG];
#pragma unroll
    for (int j = 0; j < LAG; ++j) mk[j] = mask[pix * LAG + j];

    const float scale = 0.17677669529663687f;
    float att[LAG][LAG];
#pragma unroll
    for (int i = 0; i < LAG; ++i) {
        const int tyi = ty[i];
#pragma unroll
        for (int j = 0; j < LAG; ++j) {
            uint4 s = (tyi == 0) ? kt0[j] : ((tyi == 1) ? kt1[j] : kt2[j]);
            float part;
            part = qf[i][0] * bflo(s.x);
            part = fmaf(qf[i][1], bfhi(s.x), part);
            part = fmaf(qf[i][2], bflo(s.y), part);
            part = fmaf(qf[i][3], bfhi(s.y), part);
            part = fmaf(qf[i][4], bflo(s.z), part);
            part = fmaf(qf[i][5], bfhi(s.z), part);
            part = fmaf(qf[i][6], bflo(s.w), part);
            part = fmaf(qf[i][7], bfhi(s.w), part);
            part += __shfl_xor(part, 1);
            part += __shfl_xor(part, 2);
            att[i][j] = part * scale;
        }
    }

#pragma unroll
    for (int i = 0; i < LAG; ++i) {
        float mx = -INFINITY;
#pragma unroll
        for (int j = 0; j < LAG; ++j) {
            att[i][j] = mk[j] ? att[i][j] : -INFINITY;
            mx = fmaxf(mx, att[i][j]);
        }
        float ssum = 0.f;
#pragma unroll
        for (int j = 0; j < LAG; ++j) {
            att[i][j] = __expf(att[i][j] - mx);
            ssum += att[i][j];
        }
        float inv = 1.f / ssum;
#pragma unroll
        for (int j = 0; j < LAG; ++j) att[i][j] *= inv;
    }

    uint4 vt0[LAG], vt1[LAG], vt2[LAG];
#pragma unroll
    for (int j = 0; j < LAG; ++j) {
        vt0[j] = p0 ? *(const uint4*)(vtil + (long)(0 * LAG + j) * CPL + basel) : z4;
        vt1[j] = p1 ? *(const uint4*)(vtil + (long)(1 * LAG + j) * CPL + basel) : z4;
        vt2[j] = p2 ? *(const uint4*)(vtil + (long)(2 * LAG + j) * CPL + basel) : z4;
    }

#pragma unroll
    for (int i = 0; i < LAG; ++i) {
        const int tyi = ty[i];
        float af[8] = {0.f, 0.f, 0.f, 0.f, 0.f, 0.f, 0.f, 0.f};
#pragma unroll
        for (int j = 0; j < LAG; ++j) {
            uint4 s = (tyi == 0) ? vt0[j] : ((tyi == 1) ? vt1[j] : vt2[j]);
            float wj = att[i][j];
            af[0] = fmaf(wj, bflo(s.x), af[0]); af[1] = fmaf(wj, bfhi(s.x), af[1]);
            af[2] = fmaf(wj, bflo(s.y), af[2]); af[3] = fmaf(wj, bfhi(s.y), af[3]);
            af[4] = fmaf(wj, bflo(s.z), af[4]); af[5] = fmaf(wj, bfhi(s.z), af[5]);
            af[6] = fmaf(wj, bflo(s.w), af[6]); af[7] = fmaf(wj, bfhi(s.w), af[7]);
        }
        uint4 ov;
        ov.x = pack2(af[0], af[1]); ov.y = pack2(af[2], af[3]);
        ov.z = pack2(af[4], af[5]); ov.w = pack2(af[6], af[7]);
        *(uint4*)(aws + ((long)pix * LAG + i) * CD + m * DH + o * 8) = ov;
    }
}

// ---------------------------------------------------------------------------
extern "C" void kernel_launch(void* const* d_in, const int* in_sizes, int n_in,
                              void* d_out, int out_size, void* d_ws, size_t ws_size,
                              hipStream_t stream) {
    const float* x    = (const float*)d_in[0];
    const int*   mask = (const int*)  d_in[1];
    const float* pe   = (const float*)d_in[2];
    const float* Wq   = (const float*)d_in[3];
    const float* bq   = (const float*)d_in[4];
    const float* Wk   = (const float*)d_in[5];
    const float* bk   = (const float*)d_in[6];
    const float* Wv   = (const float*)d_in[7];
    const float* bv   = (const float*)d_in[8];
    const float* Wa   = (const float*)d_in[9];
    const float* ba   = (const float*)d_in[10];
    const float* ratt = (const float*)d_in[11];
    const float* rmsg = (const float*)d_in[12];
    float* out = (float*)d_out;

    const size_t PLANE = (size_t)LAG * HW * CD;             // 22,528,000 elems
    const size_t TCH   = (size_t)NT * LAG * CHUNKMAX * CD;  // 33,914,880 elems

    unsigned short* qws   = (unsigned short*)d_ws;
    unsigned short* kws   = qws + PLANE;
    unsigned short* vws   = kws + PLANE;
    unsigned short* aws   = vws + PLANE;
    unsigned short* ktil  = aws + PLANE;
    unsigned short* vtil  = ktil + TCH;
    unsigned short* Wt    = vtil + TCH;     // 786,432 elems
    unsigned short* rattB = Wt + 786432;    // 73,728 elems
    unsigned short* rmsgT = rattB + 73728;  // 73,728 elems
    // total ~318 MB

    convert_w_kernel<<<dim3(16, 12), 256, 0, stream>>>(Wq, Wk, Wv, Wa, Wt);
    convert_rel_kernel<<<dim3(9, 8), 256, 0, stream>>>(ratt, rmsg, rattB, rmsgT);

    gemm_qkv_mfma<<<dim3(HW / 64, 1, LAG * 3), 256, 0, stream>>>(
        x, pe, Wt, bq, bk, bv, qws, kws, vws);

    const int chunk_len[2] = {8832, 8768};
    const int chunk_base[2] = {0, 8832};
    for (int c = 0; c < 2; ++c) {
        rel_precompute_mfma<<<dim3(chunk_len[c] / 64, NHEAD, LAG), 256, 0, stream>>>(
            kws, vws, rattB, rmsgT, pe, ktil, vtil, chunk_base[c]);
        attn_light_kernel<<<dim3(chunk_len[c] / 8), 256, 0, stream>>>(
            qws, ktil, vtil, mask, pe, aws, chunk_base[c]);
    }

    gemm_out_mfma<<<dim3(HW / 64, 1, LAG), 256, 0, stream>>>(aws, pe, Wt, ba, out);
}

// Round 6
// 498.523 us; speedup vs baseline: 11.9678x; 1.1150x over previous
//
#include <hip/hip_runtime.h>
#include <math.h>

#define HW     17600   // 100*176 pixels
#define CD     256     // channels == D
#define LAG    5       // agents
#define NHEAD  8
#define DH     32
#define NT     3       // agent types
#define CHUNKMAX 8832  // buffer stride (pixels); chunks are 8832 + 8768
#define KTROW  (NT * LAG * DH * NHEAD)   // 3840: interleaved kt/vt row elems

typedef short bf16x8 __attribute__((ext_vector_type(8)));
typedef float f32x4  __attribute__((ext_vector_type(4)));

// ---- bf16 helpers ----------------------------------------------------------
__device__ __forceinline__ float bflo(unsigned u) { return __uint_as_float(u << 16); }
__device__ __forceinline__ float bfhi(unsigned u) { return __uint_as_float(u & 0xffff0000u); }
__device__ __forceinline__ unsigned f2bf(float f) {
    unsigned u = __float_as_uint(f);
    return (u + 0x7fffu + ((u >> 16) & 1u)) >> 16;   // RNE
}
__device__ __forceinline__ unsigned pack2(float a, float b) {
    return f2bf(a) | (f2bf(b) << 16);
}

// ---------------------------------------------------------------------------
// convert_w: W[k][n] fp32 -> Wt[n][k] bf16, 12 matrices (q0..2,k0..2,v0..2,a0..2)
// ---------------------------------------------------------------------------
__global__ __launch_bounds__(256) void convert_w_kernel(
    const float* __restrict__ Wq, const float* __restrict__ Wk,
    const float* __restrict__ Wv, const float* __restrict__ Wa,
    unsigned short* __restrict__ Wt)
{
    __shared__ float tile[64][65];
    const int mat = blockIdx.y;
    const int k0 = (blockIdx.x >> 2) * 64;
    const int n0 = (blockIdx.x & 3) * 64;
    const float* W;
    if      (mat < 3) W = Wq + (long)mat * 65536;
    else if (mat < 6) W = Wk + (long)(mat - 3) * 65536;
    else if (mat < 9) W = Wv + (long)(mat - 6) * 65536;
    else              W = Wa + (long)(mat - 9) * 65536;
    const int t = threadIdx.x;
#pragma unroll
    for (int r = 0; r < 16; ++r) {
        int idx = r * 256 + t;
        int row = idx >> 6, col = idx & 63;
        tile[row][col] = W[(long)(k0 + row) * 256 + n0 + col];
    }
    __syncthreads();
    unsigned short* dst = Wt + (long)mat * 65536;
#pragma unroll
    for (int r = 0; r < 16; ++r) {
        int idx = r * 256 + t;
        int row = idx >> 6, col = idx & 63;
        dst[(long)(n0 + row) * 256 + k0 + col] = (unsigned short)f2bf(tile[col][row]);
    }
}

// ---------------------------------------------------------------------------
// convert_rel: rel_att -> rattB bf16 [9][8][32 p][32 q] (plain cast),
//              rel_msg -> rmsgT bf16 [9][8][32 c][32 p] (transposed).
// ---------------------------------------------------------------------------
__global__ __launch_bounds__(256) void convert_rel_kernel(
    const float* __restrict__ rel_att, const float* __restrict__ rel_msg,
    unsigned short* __restrict__ rattB, unsigned short* __restrict__ rmsgT)
{
    const long base = ((long)(blockIdx.x * NHEAD + blockIdx.y)) << 10;
    const int t = threadIdx.x;
#pragma unroll
    for (int i = 0; i < 4; ++i) {
        int idx = t * 4 + i;            // p*32+q
        int p = idx >> 5, q = idx & 31;
        rattB[base + idx] = (unsigned short)f2bf(rel_att[base + idx]);
        rmsgT[base + q * 32 + p] = (unsigned short)f2bf(rel_msg[base + idx]);
    }
}

// ---------------------------------------------------------------------------
// MFMA GEMM core: Y[64 x 256] = A[M x 256] @ Wt^T + bias.
// Linear LDS rows (64 elems) with XOR swizzle col ^= (row&7)<<3 on both the
// staging store and the fragment read -> <=2-way bank access everywhere.
// ---------------------------------------------------------------------------
template<bool AF32, bool YBF>
__device__ __forceinline__ void gemm_mfma_core(
    const void* __restrict__ Aptr, long lda,
    const unsigned short* __restrict__ Wt,
    const float* __restrict__ bias,
    void* __restrict__ Yptr, long ldy)
{
    __shared__ unsigned short As[64 * 64];
    __shared__ unsigned short Ws[256 * 64];

    const int t  = threadIdx.x;
    const int m0 = blockIdx.x * 64;
    const int w  = t >> 6;
    const int l  = t & 63;
    const int wr = w >> 1;
    const int wc = w & 1;
    const int fr = l & 15;
    const int ko = (l >> 4) << 3;

    // staging coords
    const int srow = t >> 3;                     // 0..31 per round
    const int colu = (t & 7) << 3;               // unswizzled col
    const int scol = colu ^ ((srow & 7) << 3);   // swizzled col
    // fragment-read XOR (row&7 == fr&7 for all frag rows)
    const int axor = (fr & 7) << 3;

    f32x4 acc[2][8];
#pragma unroll
    for (int i = 0; i < 2; ++i)
#pragma unroll
        for (int j = 0; j < 8; ++j) {
            acc[i][j][0] = 0.f; acc[i][j][1] = 0.f;
            acc[i][j][2] = 0.f; acc[i][j][3] = 0.f;
        }

    for (int ks = 0; ks < 4; ++ks) {
        const int k0 = ks << 6;
        __syncthreads();
        // stage A: 64 rows x 64 cols, 2 rounds
#pragma unroll
        for (int r = 0; r < 2; ++r) {
            int row = r * 32 + srow;
            if (AF32) {
                const float* src = (const float*)Aptr + (long)(m0 + row) * lda + k0 + colu;
                float4 f0 = *(const float4*)src;
                float4 f1 = *(const float4*)(src + 4);
                uint4 u;
                u.x = pack2(f0.x, f0.y); u.y = pack2(f0.z, f0.w);
                u.z = pack2(f1.x, f1.y); u.w = pack2(f1.z, f1.w);
                *(uint4*)(&As[row * 64 + scol]) = u;
            } else {
                const unsigned short* src =
                    (const unsigned short*)Aptr + (long)(m0 + row) * lda + k0 + colu;
                *(uint4*)(&As[row * 64 + scol]) = *(const uint4*)src;
            }
        }
        // stage Wt: 256 rows x 64 cols, 8 rounds
#pragma unroll
        for (int r = 0; r < 8; ++r) {
            int row = r * 32 + srow;
            *(uint4*)(&Ws[row * 64 + scol]) =
                *(const uint4*)(Wt + (long)row * 256 + k0 + colu);
        }
        __syncthreads();
#pragma unroll
        for (int kk = 0; kk < 2; ++kk) {
            const int fcol = ((kk << 5) | ko) ^ axor;
            bf16x8 a[2], b[8];
#pragma unroll
            for (int i = 0; i < 2; ++i)
                a[i] = *(const bf16x8*)(&As[(wr * 32 + i * 16 + fr) * 64 + fcol]);
#pragma unroll
            for (int j = 0; j < 8; ++j)
                b[j] = *(const bf16x8*)(&Ws[(wc * 128 + j * 16 + fr) * 64 + fcol]);
#pragma unroll
            for (int i = 0; i < 2; ++i)
#pragma unroll
                for (int j = 0; j < 8; ++j)
                    acc[i][j] = __builtin_amdgcn_mfma_f32_16x16x32_bf16(
                        a[i], b[j], acc[i][j], 0, 0, 0);
        }
    }

    const int fq = l >> 4;
#pragma unroll
    for (int j = 0; j < 8; ++j) {
        int col = wc * 128 + j * 16 + fr;
        float bz = bias[col];
#pragma unroll
        for (int i = 0; i < 2; ++i) {
            int rowb = m0 + wr * 32 + i * 16 + (fq << 2);
#pragma unroll
            for (int e = 0; e < 4; ++e) {
                float v = acc[i][j][e] + bz;
                if (YBF)
                    ((unsigned short*)Yptr)[(long)(rowb + e) * ldy + col] =
                        (unsigned short)f2bf(v);
                else
                    ((float*)Yptr)[(long)(rowb + e) * ldy + col] = v;
            }
        }
    }
}

// ---------------------------------------------------------------------------
// Kernel 1: q/k/v projections. grid (275, 1, 15)
// q written pixel-major [pix][5][256]; k,v plane-major [l][pix][256].
// ---------------------------------------------------------------------------
__global__ __launch_bounds__(256) void gemm_qkv_mfma(
    const float* __restrict__ x, const float* __restrict__ pe,
    const unsigned short* __restrict__ Wt,
    const float* __restrict__ bq, const float* __restrict__ bk,
    const float* __restrict__ bv,
    unsigned short* __restrict__ qws, unsigned short* __restrict__ kws,
    unsigned short* __restrict__ vws)
{
    const int z = blockIdx.z;
    const int lag = z / 3, proj = z % 3;
    const int tpe = (int)pe[lag * 3 + 2];
    const float* A = x + (long)lag * HW * CD;
    const unsigned short* Wm = Wt + (long)(proj * 3 + tpe) * 65536;
    const float* bias;
    unsigned short* Y;
    long ldy;
    if      (proj == 0) { bias = bq; Y = qws + (long)lag * CD; ldy = LAG * CD; }
    else if (proj == 1) { bias = bk; Y = kws + (long)lag * HW * CD; ldy = CD; }
    else                { bias = bv; Y = vws + (long)lag * HW * CD; ldy = CD; }
    bias += tpe * CD;
    gemm_mfma_core<true, true>(A, CD, Wm, bias, Y, ldy);
}

// ---------------------------------------------------------------------------
// Kernel 4: output projection. grid (275, 1, 5). A = aws [pix][5][256].
// ---------------------------------------------------------------------------
__global__ __launch_bounds__(256) void gemm_out_mfma(
    const unsigned short* __restrict__ aws, const float* __restrict__ pe,
    const unsigned short* __restrict__ Wt, const float* __restrict__ ba,
    float* __restrict__ out)
{
    const int lag = blockIdx.z;
    const int tpe = (int)pe[lag * 3 + 2];
    const unsigned short* A = aws + (long)lag * CD;
    const unsigned short* Wm = Wt + (long)(9 + tpe) * 65536;
    const float* bias = ba + tpe * CD;
    float* Y = out + (long)lag * HW * CD;
    gemm_mfma_core<false, false>(A, (long)LAG * CD, Wm, bias, Y, CD);
}

// ---------------------------------------------------------------------------
// Kernel 2: relational precompute via MFMA, K=32 GEMM per (tau, j, head).
// Output pixel-major interleaved: ktil[pl][tau*5+j][m*32+p] (row = 3840 elems)
// grid (chunk_len/64, 8, 5), block 256 = 4 waves; each wave owns 16 pixels.
// ---------------------------------------------------------------------------
__global__ __launch_bounds__(256) void rel_precompute_mfma(
    const unsigned short* __restrict__ kws, const unsigned short* __restrict__ vws,
    const unsigned short* __restrict__ rattB, const unsigned short* __restrict__ rmsgT,
    const float* __restrict__ pe,
    unsigned short* __restrict__ ktil, unsigned short* __restrict__ vtil,
    int pix_base)
{
    const int j = blockIdx.z;
    const int m = blockIdx.y;
    const int t = threadIdx.x;
    const int w = t >> 6;
    const int l = t & 63;
    const int col = l & 15;
    const int ko  = (l >> 4) << 3;

    int ty[LAG];
#pragma unroll
    for (int i = 0; i < LAG; ++i) ty[i] = (int)pe[i * 3 + 2];
    bool pres[NT] = {false, false, false};
#pragma unroll
    for (int i = 0; i < LAG; ++i) {
        pres[0] = pres[0] || (ty[i] == 0);
        pres[1] = pres[1] || (ty[i] == 1);
        pres[2] = pres[2] || (ty[i] == 2);
    }
    const int tyj = ty[j];

    const int pl0 = blockIdx.x * 64 + w * 16;
    const int pix = pix_base + pl0 + col;

    const long kvoff = ((long)j * HW + pix) * CD + m * DH + ko;
    bf16x8 Ak = *(const bf16x8*)(kws + kvoff);
    bf16x8 Av = *(const bf16x8*)(vws + kvoff);

    const int prow = (l >> 4) << 2;

#pragma unroll
    for (int tau = 0; tau < NT; ++tau) {
        if (!pres[tau]) continue;
        const int e = tau * NT + tyj;
        const unsigned short* bk = rattB + ((long)(e * NHEAD + m) << 10);
        const unsigned short* bv = rmsgT + ((long)(e * NHEAD + m) << 10);

        bf16x8 Bk0 = *(const bf16x8*)(bk + col * 32 + ko);
        bf16x8 Bk1 = *(const bf16x8*)(bk + (col + 16) * 32 + ko);
        bf16x8 Bv0 = *(const bf16x8*)(bv + col * 32 + ko);
        bf16x8 Bv1 = *(const bf16x8*)(bv + (col + 16) * 32 + ko);

        f32x4 z = {0.f, 0.f, 0.f, 0.f};
        f32x4 ck0 = __builtin_amdgcn_mfma_f32_16x16x32_bf16(Ak, Bk0, z, 0, 0, 0);
        f32x4 ck1 = __builtin_amdgcn_mfma_f32_16x16x32_bf16(Ak, Bk1, z, 0, 0, 0);
        f32x4 cv0 = __builtin_amdgcn_mfma_f32_16x16x32_bf16(Av, Bv0, z, 0, 0, 0);
        f32x4 cv1 = __builtin_amdgcn_mfma_f32_16x16x32_bf16(Av, Bv1, z, 0, 0, 0);

        const long pbase = (long)(tau * LAG + j) * CD + m * DH;
#pragma unroll
        for (int e4 = 0; e4 < 4; ++e4) {
            const long ob = (long)(pl0 + prow + e4) * KTROW + pbase;
            ktil[ob + col]      = (unsigned short)f2bf(ck0[e4]);
            ktil[ob + 16 + col] = (unsigned short)f2bf(ck1[e4]);
            vtil[ob + col]      = (unsigned short)f2bf(cv0[e4]);
            vtil[ob + 16 + col] = (unsigned short)f2bf(cv1[e4]);
        }
    }
}

// ---------------------------------------------------------------------------
// Kernel 3: attention. 4-lane groups own (pixel, head); each lane holds 8 dims.
// All reads from pixel-local windows: q 2.5KB, ktil/vtil 7.5KB each.
// grid.x = chunk_len/8, block 256.
// ---------------------------------------------------------------------------
__global__ __launch_bounds__(256) void attn_light_kernel(
    const unsigned short* __restrict__ qws,    // [pix][5][256]
    const unsigned short* __restrict__ ktil,   // [pl][15][256]
    const unsigned short* __restrict__ vtil,   // [pl][15][256]
    const int* __restrict__ mask, const float* __restrict__ pe,
    unsigned short* __restrict__ aws, int pix_base)
{
    const int t = threadIdx.x;
    const int gid = blockIdx.x * 256 + t;
    const int o = gid & 3;
    const int grp = gid >> 2;
    const int m = grp & 7;
    const int pl = grp >> 3;
    const int pix = pix_base + pl;

    int ty[LAG];
#pragma unroll
    for (int i = 0; i < LAG; ++i) ty[i] = (int)pe[i * 3 + 2];
    bool p0 = false, p1 = false, p2 = false;
#pragma unroll
    for (int i = 0; i < LAG; ++i) {
        p0 = p0 || (ty[i] == 0); p1 = p1 || (ty[i] == 1); p2 = p2 || (ty[i] == 2);
    }

    const long baseg = (long)pix * (LAG * CD) + m * DH + o * 8;
    const long basel = (long)pl * KTROW + m * DH + o * 8;

    float qf[LAG][8];
#pragma unroll
    for (int i = 0; i < LAG; ++i) {
        uint4 u = *(const uint4*)(qws + baseg + i * CD);
        qf[i][0] = bflo(u.x); qf[i][1] = bfhi(u.x);
        qf[i][2] = bflo(u.y); qf[i][3] = bfhi(u.y);
        qf[i][4] = bflo(u.z); qf[i][5] = bfhi(u.z);
        qf[i][6] = bflo(u.w); qf[i][7] = bfhi(u.w);
    }

    const uint4 z4 = make_uint4(0, 0, 0, 0);
    uint4 kt0[LAG], kt1[LAG], kt2[LAG];
#pragma unroll
    for (int j = 0; j < LAG; ++j) {
        kt0[j] = p0 ? *(const uint4*)(ktil + basel + (0 * LAG + j) * CD) : z4;
        kt1[j] = p1 ? *(const uint4*)(ktil + basel + (1 * LAG + j) * CD) : z4;
        kt2[j] = p2 ? *(const uint4*)(ktil + basel + (2 * LAG + j) * CD) : z4;
    }

    int mk[LAG];
#pragma unroll
    for (int j = 0; j < LAG; ++j) mk[j] = mask[pix * LAG + j];

    const float scale = 0.17677669529663687f;
    float att[LAG][LAG];
#pragma unroll
    for (int i = 0; i < LAG; ++i) {
        const int tyi = ty[i];
#pragma unroll
        for (int j = 0; j < LAG; ++j) {
            uint4 s = (tyi == 0) ? kt0[j] : ((tyi == 1) ? kt1[j] : kt2[j]);
            float part;
            part = qf[i][0] * bflo(s.x);
            part = fmaf(qf[i][1], bfhi(s.x), part);
            part = fmaf(qf[i][2], bflo(s.y), part);
            part = fmaf(qf[i][3], bfhi(s.y), part);
            part = fmaf(qf[i][4], bflo(s.z), part);
            part = fmaf(qf[i][5], bfhi(s.z), part);
            part = fmaf(qf[i][6], bflo(s.w), part);
            part = fmaf(qf[i][7], bfhi(s.w), part);
            part += __shfl_xor(part, 1);
            part += __shfl_xor(part, 2);
            att[i][j] = part * scale;
        }
    }

#pragma unroll
    for (int i = 0; i < LAG; ++i) {
        float mx = -INFINITY;
#pragma unroll
        for (int j = 0; j < LAG; ++j) {
            att[i][j] = mk[j] ? att[i][j] : -INFINITY;
            mx = fmaxf(mx, att[i][j]);
        }
        float ssum = 0.f;
#pragma unroll
        for (int j = 0; j < LAG; ++j) {
            att[i][j] = __expf(att[i][j] - mx);
            ssum += att[i][j];
        }
        float inv = 1.f / ssum;
#pragma unroll
        for (int j = 0; j < LAG; ++j) att[i][j] *= inv;
    }

    uint4 vt0[LAG], vt1[LAG], vt2[LAG];
#pragma unroll
    for (int j = 0; j < LAG; ++j) {
        vt0[j] = p0 ? *(const uint4*)(vtil + basel + (0 * LAG + j) * CD) : z4;
        vt1[j] = p1 ? *(const uint4*)(vtil + basel + (1 * LAG + j) * CD) : z4;
        vt2[j] = p2 ? *(const uint4*)(vtil + basel + (2 * LAG + j) * CD) : z4;
    }

#pragma unroll
    for (int i = 0; i < LAG; ++i) {
        const int tyi = ty[i];
        float af[8] = {0.f, 0.f, 0.f, 0.f, 0.f, 0.f, 0.f, 0.f};
#pragma unroll
        for (int j = 0; j < LAG; ++j) {
            uint4 s = (tyi == 0) ? vt0[j] : ((tyi == 1) ? vt1[j] : vt2[j]);
            float wj = att[i][j];
            af[0] = fmaf(wj, bflo(s.x), af[0]); af[1] = fmaf(wj, bfhi(s.x), af[1]);
            af[2] = fmaf(wj, bflo(s.y), af[2]); af[3] = fmaf(wj, bfhi(s.y), af[3]);
            af[4] = fmaf(wj, bflo(s.z), af[4]); af[5] = fmaf(wj, bfhi(s.z), af[5]);
            af[6] = fmaf(wj, bflo(s.w), af[6]); af[7] = fmaf(wj, bfhi(s.w), af[7]);
        }
        uint4 ov;
        ov.x = pack2(af[0], af[1]); ov.y = pack2(af[2], af[3]);
        ov.z = pack2(af[4], af[5]); ov.w = pack2(af[6], af[7]);
        *(uint4*)(aws + (long)pix * (LAG * CD) + i * CD + m * DH + o * 8) = ov;
    }
}

// ---------------------------------------------------------------------------
extern "C" void kernel_launch(void* const* d_in, const int* in_sizes, int n_in,
                              void* d_out, int out_size, void* d_ws, size_t ws_size,
                              hipStream_t stream) {
    const float* x    = (const float*)d_in[0];
    const int*   mask = (const int*)  d_in[1];
    const float* pe   = (const float*)d_in[2];
    const float* Wq   = (const float*)d_in[3];
    const float* bq   = (const float*)d_in[4];
    const float* Wk   = (const float*)d_in[5];
    const float* bk   = (const float*)d_in[6];
    const float* Wv   = (const float*)d_in[7];
    const float* bv   = (const float*)d_in[8];
    const float* Wa   = (const float*)d_in[9];
    const float* ba   = (const float*)d_in[10];
    const float* ratt = (const float*)d_in[11];
    const float* rmsg = (const float*)d_in[12];
    float* out = (float*)d_out;

    const size_t PLANE = (size_t)LAG * HW * CD;             // 22,528,000 elems
    const size_t TCH   = (size_t)CHUNKMAX * KTROW;          // 33,914,880 elems

    unsigned short* qws   = (unsigned short*)d_ws;          // [pix][5][256]
    unsigned short* kws   = qws + PLANE;                    // [5][pix][256]
    unsigned short* vws   = kws + PLANE;
    unsigned short* aws   = vws + PLANE;                    // [pix][5][256]
    unsigned short* ktil  = aws + PLANE;                    // [pl][15][256]
    unsigned short* vtil  = ktil + TCH;
    unsigned short* Wt    = vtil + TCH;     // 786,432 elems
    unsigned short* rattB = Wt + 786432;    // 73,728 elems
    unsigned short* rmsgT = rattB + 73728;  // 73,728 elems
    // total ~318 MB

    convert_w_kernel<<<dim3(16, 12), 256, 0, stream>>>(Wq, Wk, Wv, Wa, Wt);
    convert_rel_kernel<<<dim3(9, 8), 256, 0, stream>>>(ratt, rmsg, rattB, rmsgT);

    gemm_qkv_mfma<<<dim3(HW / 64, 1, LAG * 3), 256, 0, stream>>>(
        x, pe, Wt, bq, bk, bv, qws, kws, vws);

    const int chunk_len[2] = {8832, 8768};
    const int chunk_base[2] = {0, 8832};
    for (int c = 0; c < 2; ++c) {
        rel_precompute_mfma<<<dim3(chunk_len[c] / 64, NHEAD, LAG), 256, 0, stream>>>(
            kws, vws, rattB, rmsgT, pe, ktil, vtil, chunk_base[c]);
        attn_light_kernel<<<dim3(chunk_len[c] / 8), 256, 0, stream>>>(
            qws, ktil, vtil, mask, pe, aws, chunk_base[c]);
    }

    gemm_out_mfma<<<dim3(HW / 64, 1, LAG), 256, 0, stream>>>(aws, pe, Wt, ba, out);
}

// Round 7
// 210.188 us; speedup vs baseline: 28.3853x; 2.3718x over previous
//
#include <hip/hip_runtime.h>
#include <math.h>

#define HW     17600   // 100*176 pixels
#define CD     256     // channels == D
#define LAG    5       // agents
#define NHEAD  8
#define DH     32
#define NT     3       // agent types

typedef short bf16x8 __attribute__((ext_vector_type(8)));
typedef float f32x4  __attribute__((ext_vector_type(4)));

// ---- bf16 helpers ----------------------------------------------------------
__device__ __forceinline__ float bflo(unsigned u) { return __uint_as_float(u << 16); }
__device__ __forceinline__ float bfhi(unsigned u) { return __uint_as_float(u & 0xffff0000u); }
__device__ __forceinline__ unsigned f2bf(float f) {
    unsigned u = __float_as_uint(f);
    return (u + 0x7fffu + ((u >> 16) & 1u)) >> 16;   // RNE
}
__device__ __forceinline__ unsigned pack2(float a, float b) {
    return f2bf(a) | (f2bf(b) << 16);
}

// ---------------------------------------------------------------------------
// convert_w: W[k][n] fp32 -> Wt[n][k] bf16, 12 matrices (q0..2,k0..2,v0..2,a0..2)
// ---------------------------------------------------------------------------
__global__ __launch_bounds__(256) void convert_w_kernel(
    const float* __restrict__ Wq, const float* __restrict__ Wk,
    const float* __restrict__ Wv, const float* __restrict__ Wa,
    unsigned short* __restrict__ Wt)
{
    __shared__ float tile[64][65];
    const int mat = blockIdx.y;
    const int k0 = (blockIdx.x >> 2) * 64;
    const int n0 = (blockIdx.x & 3) * 64;
    const float* W;
    if      (mat < 3) W = Wq + (long)mat * 65536;
    else if (mat < 6) W = Wk + (long)(mat - 3) * 65536;
    else if (mat < 9) W = Wv + (long)(mat - 6) * 65536;
    else              W = Wa + (long)(mat - 9) * 65536;
    const int t = threadIdx.x;
#pragma unroll
    for (int r = 0; r < 16; ++r) {
        int idx = r * 256 + t;
        int row = idx >> 6, col = idx & 63;
        tile[row][col] = W[(long)(k0 + row) * 256 + n0 + col];
    }
    __syncthreads();
    unsigned short* dst = Wt + (long)mat * 65536;
#pragma unroll
    for (int r = 0; r < 16; ++r) {
        int idx = r * 256 + t;
        int row = idx >> 6, col = idx & 63;
        dst[(long)(n0 + row) * 256 + k0 + col] = (unsigned short)f2bf(tile[col][row]);
    }
}

// ---------------------------------------------------------------------------
// convert_rel: rel_att -> rattT bf16 [9][8][32 q][32 p] (transposed),
//              rel_msg -> rmsgT bf16 [9][8][32 c][32 p] (transposed).
// Both used as MFMA B-frags with contraction over p.
// ---------------------------------------------------------------------------
__global__ __launch_bounds__(256) void convert_rel_kernel(
    const float* __restrict__ rel_att, const float* __restrict__ rel_msg,
    unsigned short* __restrict__ rattT, unsigned short* __restrict__ rmsgT)
{
    const long base = ((long)(blockIdx.x * NHEAD + blockIdx.y)) << 10;
    const int t = threadIdx.x;
#pragma unroll
    for (int i = 0; i < 4; ++i) {
        int idx = t * 4 + i;            // p*32+q
        int p = idx >> 5, q = idx & 31;
        rattT[base + q * 32 + p] = (unsigned short)f2bf(rel_att[base + idx]);
        rmsgT[base + q * 32 + p] = (unsigned short)f2bf(rel_msg[base + idx]);
    }
}

// ---------------------------------------------------------------------------
// MFMA GEMM core: Y[64 x 256] = A[M x 256] @ Wt^T + bias. (unchanged, passing)
// ---------------------------------------------------------------------------
template<bool AF32, bool YBF>
__device__ __forceinline__ void gemm_mfma_core(
    const void* __restrict__ Aptr, long lda,
    const unsigned short* __restrict__ Wt,
    const float* __restrict__ bias,
    void* __restrict__ Yptr, long ldy)
{
    __shared__ unsigned short As[64 * 64];
    __shared__ unsigned short Ws[256 * 64];

    const int t  = threadIdx.x;
    const int m0 = blockIdx.x * 64;
    const int w  = t >> 6;
    const int l  = t & 63;
    const int wr = w >> 1;
    const int wc = w & 1;
    const int fr = l & 15;
    const int ko = (l >> 4) << 3;

    const int srow = t >> 3;
    const int colu = (t & 7) << 3;
    const int scol = colu ^ ((srow & 7) << 3);
    const int axor = (fr & 7) << 3;

    f32x4 acc[2][8];
#pragma unroll
    for (int i = 0; i < 2; ++i)
#pragma unroll
        for (int j = 0; j < 8; ++j) {
            acc[i][j][0] = 0.f; acc[i][j][1] = 0.f;
            acc[i][j][2] = 0.f; acc[i][j][3] = 0.f;
        }

    for (int ks = 0; ks < 4; ++ks) {
        const int k0 = ks << 6;
        __syncthreads();
#pragma unroll
        for (int r = 0; r < 2; ++r) {
            int row = r * 32 + srow;
            if (AF32) {
                const float* src = (const float*)Aptr + (long)(m0 + row) * lda + k0 + colu;
                float4 f0 = *(const float4*)src;
                float4 f1 = *(const float4*)(src + 4);
                uint4 u;
                u.x = pack2(f0.x, f0.y); u.y = pack2(f0.z, f0.w);
                u.z = pack2(f1.x, f1.y); u.w = pack2(f1.z, f1.w);
                *(uint4*)(&As[row * 64 + scol]) = u;
            } else {
                const unsigned short* src =
                    (const unsigned short*)Aptr + (long)(m0 + row) * lda + k0 + colu;
                *(uint4*)(&As[row * 64 + scol]) = *(const uint4*)src;
            }
        }
#pragma unroll
        for (int r = 0; r < 8; ++r) {
            int row = r * 32 + srow;
            *(uint4*)(&Ws[row * 64 + scol]) =
                *(const uint4*)(Wt + (long)row * 256 + k0 + colu);
        }
        __syncthreads();
#pragma unroll
        for (int kk = 0; kk < 2; ++kk) {
            const int fcol = ((kk << 5) | ko) ^ axor;
            bf16x8 a[2], b[8];
#pragma unroll
            for (int i = 0; i < 2; ++i)
                a[i] = *(const bf16x8*)(&As[(wr * 32 + i * 16 + fr) * 64 + fcol]);
#pragma unroll
            for (int j = 0; j < 8; ++j)
                b[j] = *(const bf16x8*)(&Ws[(wc * 128 + j * 16 + fr) * 64 + fcol]);
#pragma unroll
            for (int i = 0; i < 2; ++i)
#pragma unroll
                for (int j = 0; j < 8; ++j)
                    acc[i][j] = __builtin_amdgcn_mfma_f32_16x16x32_bf16(
                        a[i], b[j], acc[i][j], 0, 0, 0);
        }
    }

    const int fq = l >> 4;
#pragma unroll
    for (int j = 0; j < 8; ++j) {
        int col = wc * 128 + j * 16 + fr;
        float bz = bias[col];
#pragma unroll
        for (int i = 0; i < 2; ++i) {
            int rowb = m0 + wr * 32 + i * 16 + (fq << 2);
#pragma unroll
            for (int e = 0; e < 4; ++e) {
                float v = acc[i][j][e] + bz;
                if (YBF)
                    ((unsigned short*)Yptr)[(long)(rowb + e) * ldy + col] =
                        (unsigned short)f2bf(v);
                else
                    ((float*)Yptr)[(long)(rowb + e) * ldy + col] = v;
            }
        }
    }
}

// ---------------------------------------------------------------------------
// Kernel 1: q/k/v projections. grid (275, 1, 15)
// q -> [pix][5][256]; k,v -> [l][pix][256].
// ---------------------------------------------------------------------------
__global__ __launch_bounds__(256) void gemm_qkv_mfma(
    const float* __restrict__ x, const float* __restrict__ pe,
    const unsigned short* __restrict__ Wt,
    const float* __restrict__ bq, const float* __restrict__ bk,
    const float* __restrict__ bv,
    unsigned short* __restrict__ qws, unsigned short* __restrict__ kws,
    unsigned short* __restrict__ vws)
{
    const int z = blockIdx.z;
    const int lag = z / 3, proj = z % 3;
    const int tpe = (int)pe[lag * 3 + 2];
    const float* A = x + (long)lag * HW * CD;
    const unsigned short* Wm = Wt + (long)(proj * 3 + tpe) * 65536;
    const float* bias;
    unsigned short* Y;
    long ldy;
    if      (proj == 0) { bias = bq; Y = qws + (long)lag * CD; ldy = LAG * CD; }
    else if (proj == 1) { bias = bk; Y = kws + (long)lag * HW * CD; ldy = CD; }
    else                { bias = bv; Y = vws + (long)lag * HW * CD; ldy = CD; }
    bias += tpe * CD;
    gemm_mfma_core<true, true>(A, CD, Wm, bias, Y, ldy);
}

// ---------------------------------------------------------------------------
// Kernel 3: output projection. grid (275, 1, 5). A = aws [pix][5][256].
// ---------------------------------------------------------------------------
__global__ __launch_bounds__(256) void gemm_out_mfma(
    const unsigned short* __restrict__ aws, const float* __restrict__ pe,
    const unsigned short* __restrict__ Wt, const float* __restrict__ ba,
    float* __restrict__ out)
{
    const int lag = blockIdx.z;
    const int tpe = (int)pe[lag * 3 + 2];
    const unsigned short* A = aws + (long)lag * CD;
    const unsigned short* Wm = Wt + (long)(9 + tpe) * 65536;
    const float* bias = ba + tpe * CD;
    float* Y = out + (long)lag * HW * CD;
    gemm_mfma_core<false, false>(A, (long)LAG * CD, Wm, bias, Y, CD);
}

// ---------------------------------------------------------------------------
// Kernel 2 (FUSED attention): per block = 64 pixels x 1 head, 256 thr = 4 waves.
// Phase 1 (per wave, 16 pixels): qt[i][sigma] = W_att[ty_i,sigma]^T q[i] via
//   MFMA (A = q frag, B = rattT), store bf16 -> LDS (row padded to 488 elems).
// Phase 2 (thread = (pixel, q-octet)): logit[i][j] = qt[i][ty_j] . k[j]
//   (8-FMA + quad shfl reduce), masked softmax -> att[i][j] in regs.
// Phase 3: vagg[i] = sum_{j: ty_j=sigma} att[i][j] v[j] -> LDS (row 168),
//   out[i] += MFMA(vagg[i], rmsgT[ty_i*3+sigma]); accumulate over sigma.
// ktil/vtil never materialize; all LDS rows give <=2-way bank access.
// ---------------------------------------------------------------------------
#define QTROW 488   // 5*3*32 = 480 + 8 pad (2-way banks)
#define VGROW 168   // 5*32 = 160 + 8 pad (2-way banks)

__global__ __launch_bounds__(256) void attn_fused_kernel(
    const unsigned short* __restrict__ qws,    // [pix][5][256]
    const unsigned short* __restrict__ kws,    // [j][pix][256]
    const unsigned short* __restrict__ vws,    // [j][pix][256]
    const unsigned short* __restrict__ rattT,  // [9][8][32 q][32 p]
    const unsigned short* __restrict__ rmsgT,  // [9][8][32 c][32 p]
    const int* __restrict__ mask, const float* __restrict__ pe,
    unsigned short* __restrict__ aws)          // [pix][5][256]
{
    __shared__ unsigned short lds[4 * 16 * QTROW];   // 62.5 KB

    const int t    = threadIdx.x;
    const int w    = t >> 6;
    const int l    = t & 63;
    const int fr   = l & 15;
    const int fq   = l >> 4;
    const int m    = blockIdx.y;
    const int pix0 = blockIdx.x * 64;

    // phase-2/3 thread mapping
    const int pl2   = t >> 2;          // 0..63 local pixel
    const int sub   = t & 3;           // q/p octet
    const int gpix2 = pix0 + pl2;

    int ty[LAG];
#pragma unroll
    for (int i = 0; i < LAG; ++i) ty[i] = (int)pe[i * 3 + 2];
    bool pres[NT] = {false, false, false};
#pragma unroll
    for (int i = 0; i < LAG; ++i) {
        pres[0] = pres[0] || (ty[i] == 0);
        pres[1] = pres[1] || (ty[i] == 1);
        pres[2] = pres[2] || (ty[i] == 2);
    }

    // ---- early global loads (k, v, mask) for MLP --------------------------
    uint4 kf[LAG], vf[LAG];
    int mk[LAG];
#pragma unroll
    for (int j = 0; j < LAG; ++j) {
        const long off = ((long)j * HW + gpix2) * CD + m * DH + sub * 8;
        kf[j] = *(const uint4*)(kws + off);
        vf[j] = *(const uint4*)(vws + off);
        mk[j] = mask[gpix2 * LAG + j];
    }

    // ---- phase 1: qt via MFMA ---------------------------------------------
    {
        bf16x8 aq[LAG];
#pragma unroll
        for (int i = 0; i < LAG; ++i)
            aq[i] = *(const bf16x8*)(qws + (long)(pix0 + w * 16 + fr) * (LAG * CD)
                                     + i * CD + m * DH + fq * 8);
        const int qtbase = w * 16 * QTROW;
#pragma unroll
        for (int sg = 0; sg < NT; ++sg) {
            if (!pres[sg]) continue;
#pragma unroll
            for (int i = 0; i < LAG; ++i) {
                const int e = ty[i] * NT + sg;
                const unsigned short* bb = rattT + ((long)(e * NHEAD + m) << 10);
                bf16x8 b0 = *(const bf16x8*)(bb + fr * 32 + fq * 8);
                bf16x8 b1 = *(const bf16x8*)(bb + (fr + 16) * 32 + fq * 8);
                f32x4 z = {0.f, 0.f, 0.f, 0.f};
                f32x4 d0 = __builtin_amdgcn_mfma_f32_16x16x32_bf16(aq[i], b0, z, 0, 0, 0);
                f32x4 d1 = __builtin_amdgcn_mfma_f32_16x16x32_bf16(aq[i], b1, z, 0, 0, 0);
#pragma unroll
                for (int e4 = 0; e4 < 4; ++e4) {
                    const int idx = qtbase + (fq * 4 + e4) * QTROW + (i * NT + sg) * 32;
                    lds[idx + fr]      = (unsigned short)f2bf(d0[e4]);
                    lds[idx + fr + 16] = (unsigned short)f2bf(d1[e4]);
                }
            }
        }
    }
    __syncthreads();

    // ---- phase 2: logits + softmax -----------------------------------------
    const float scale = 0.17677669529663687f;  // 32^-0.5
    float att[LAG][LAG];
    {
        const int qtb = w * 16 * QTROW + (pl2 & 15) * QTROW;
#pragma unroll
        for (int j = 0; j < LAG; ++j) {
            float kx[8];
            kx[0] = bflo(kf[j].x); kx[1] = bfhi(kf[j].x);
            kx[2] = bflo(kf[j].y); kx[3] = bfhi(kf[j].y);
            kx[4] = bflo(kf[j].z); kx[5] = bfhi(kf[j].z);
            kx[6] = bflo(kf[j].w); kx[7] = bfhi(kf[j].w);
            const int tyj = ty[j];
#pragma unroll
            for (int i = 0; i < LAG; ++i) {
                uint4 qv = *(const uint4*)(&lds[qtb + (i * NT + tyj) * 32 + sub * 8]);
                float part;
                part = bflo(qv.x) * kx[0];
                part = fmaf(bfhi(qv.x), kx[1], part);
                part = fmaf(bflo(qv.y), kx[2], part);
                part = fmaf(bfhi(qv.y), kx[3], part);
                part = fmaf(bflo(qv.z), kx[4], part);
                part = fmaf(bfhi(qv.z), kx[5], part);
                part = fmaf(bflo(qv.w), kx[6], part);
                part = fmaf(bfhi(qv.w), kx[7], part);
                part += __shfl_xor(part, 1);
                part += __shfl_xor(part, 2);
                att[i][j] = part * scale;
            }
        }
#pragma unroll
        for (int i = 0; i < LAG; ++i) {
            float mx = -INFINITY;
#pragma unroll
            for (int j = 0; j < LAG; ++j) {
                att[i][j] = mk[j] ? att[i][j] : -INFINITY;
                mx = fmaxf(mx, att[i][j]);
            }
            float ssum = 0.f;
#pragma unroll
            for (int j = 0; j < LAG; ++j) {
                att[i][j] = __expf(att[i][j] - mx);
                ssum += att[i][j];
            }
            float inv = 1.f / ssum;
#pragma unroll
            for (int j = 0; j < LAG; ++j) att[i][j] *= inv;
        }
    }

    // unpack v once
    float vx[LAG][8];
#pragma unroll
    for (int j = 0; j < LAG; ++j) {
        vx[j][0] = bflo(vf[j].x); vx[j][1] = bfhi(vf[j].x);
        vx[j][2] = bflo(vf[j].y); vx[j][3] = bfhi(vf[j].y);
        vx[j][4] = bflo(vf[j].z); vx[j][5] = bfhi(vf[j].z);
        vx[j][6] = bflo(vf[j].w); vx[j][7] = bfhi(vf[j].w);
    }

    // ---- phase 3: vagg + MFMA message transform, accumulate over sigma ----
    f32x4 oacc[LAG][2];
#pragma unroll
    for (int i = 0; i < LAG; ++i)
#pragma unroll
        for (int c = 0; c < 2; ++c) {
            oacc[i][c][0] = 0.f; oacc[i][c][1] = 0.f;
            oacc[i][c][2] = 0.f; oacc[i][c][3] = 0.f;
        }

    const int vgw = w * 16 * QTROW;   // vagg region aliases qt region
    for (int sg = 0; sg < NT; ++sg) {
        if (!pres[sg]) continue;
        __syncthreads();   // prev MFMA reads done before overwrite
#pragma unroll
        for (int i = 0; i < LAG; ++i) {
            float vg[8] = {0.f,0.f,0.f,0.f,0.f,0.f,0.f,0.f};
#pragma unroll
            for (int j = 0; j < LAG; ++j) {
                float wj = (ty[j] == sg) ? att[i][j] : 0.f;
#pragma unroll
                for (int d = 0; d < 8; ++d) vg[d] = fmaf(wj, vx[j][d], vg[d]);
            }
            uint4 o;
            o.x = pack2(vg[0], vg[1]); o.y = pack2(vg[2], vg[3]);
            o.z = pack2(vg[4], vg[5]); o.w = pack2(vg[6], vg[7]);
            *(uint4*)(&lds[vgw + (pl2 & 15) * VGROW + i * 32 + sub * 8]) = o;
        }
        __syncthreads();
#pragma unroll
        for (int i = 0; i < LAG; ++i) {
            bf16x8 a = *(const bf16x8*)(&lds[vgw + fr * VGROW + i * 32 + fq * 8]);
            const int e = ty[i] * NT + sg;
            const unsigned short* bb = rmsgT + ((long)(e * NHEAD + m) << 10);
            bf16x8 b0 = *(const bf16x8*)(bb + fr * 32 + fq * 8);
            bf16x8 b1 = *(const bf16x8*)(bb + (fr + 16) * 32 + fq * 8);
            oacc[i][0] = __builtin_amdgcn_mfma_f32_16x16x32_bf16(a, b0, oacc[i][0], 0, 0, 0);
            oacc[i][1] = __builtin_amdgcn_mfma_f32_16x16x32_bf16(a, b1, oacc[i][1], 0, 0, 0);
        }
    }

    // ---- store: lane holds out[pix=fq*4+e][c=fr, fr+16] --------------------
#pragma unroll
    for (int i = 0; i < LAG; ++i) {
#pragma unroll
        for (int e4 = 0; e4 < 4; ++e4) {
            const long ob = (long)(pix0 + w * 16 + fq * 4 + e4) * (LAG * CD)
                            + i * CD + m * DH;
            aws[ob + fr]      = (unsigned short)f2bf(oacc[i][0][e4]);
            aws[ob + fr + 16] = (unsigned short)f2bf(oacc[i][1][e4]);
        }
    }
}

// ---------------------------------------------------------------------------
extern "C" void kernel_launch(void* const* d_in, const int* in_sizes, int n_in,
                              void* d_out, int out_size, void* d_ws, size_t ws_size,
                              hipStream_t stream) {
    const float* x    = (const float*)d_in[0];
    const int*   mask = (const int*)  d_in[1];
    const float* pe   = (const float*)d_in[2];
    const float* Wq   = (const float*)d_in[3];
    const float* bq   = (const float*)d_in[4];
    const float* Wk   = (const float*)d_in[5];
    const float* bk   = (const float*)d_in[6];
    const float* Wv   = (const float*)d_in[7];
    const float* bv   = (const float*)d_in[8];
    const float* Wa   = (const float*)d_in[9];
    const float* ba   = (const float*)d_in[10];
    const float* ratt = (const float*)d_in[11];
    const float* rmsg = (const float*)d_in[12];
    float* out = (float*)d_out;

    const size_t PLANE = (size_t)LAG * HW * CD;   // 22,528,000 elems

    unsigned short* qws   = (unsigned short*)d_ws;          // [pix][5][256]
    unsigned short* kws   = qws + PLANE;                    // [5][pix][256]
    unsigned short* vws   = kws + PLANE;
    unsigned short* aws   = vws + PLANE;                    // [pix][5][256]
    unsigned short* Wt    = aws + PLANE;    // 786,432 elems
    unsigned short* rattT = Wt + 786432;    // 73,728 elems
    unsigned short* rmsgT = rattT + 73728;  // 73,728 elems
    // total ~182 MB

    convert_w_kernel<<<dim3(16, 12), 256, 0, stream>>>(Wq, Wk, Wv, Wa, Wt);
    convert_rel_kernel<<<dim3(9, 8), 256, 0, stream>>>(ratt, rmsg, rattT, rmsgT);

    gemm_qkv_mfma<<<dim3(HW / 64, 1, LAG * 3), 256, 0, stream>>>(
        x, pe, Wt, bq, bk, bv, qws, kws, vws);

    attn_fused_kernel<<<dim3(HW / 64, NHEAD), 256, 0, stream>>>(
        qws, kws, vws, rattT, rmsgT, mask, pe, aws);

    gemm_out_mfma<<<dim3(HW / 64, 1, LAG), 256, 0, stream>>>(aws, pe, Wt, ba, out);
}